// Round 2
// baseline (1498.438 us; speedup 1.0000x reference)
//
#include <hip/hip_runtime.h>
#include <stdint.h>

#define B_ 8
#define N_ 1024
#define C_ 768
#define H_ 12
#define D_ 64
#define G_ 6

__device__ __forceinline__ float bf2f(unsigned short u) {
  return __uint_as_float(((unsigned)u) << 16);
}
__device__ __forceinline__ unsigned short f2bf(float f) {
  unsigned x = __float_as_uint(f);
  unsigned r = x + 0x7fffu + ((x >> 16) & 1u);  // RNE
  return (unsigned short)(r >> 16);
}

// ---------- projection GEMM: out(bf16, BHND layout) = X @ W^T + bias -------
__global__ __launch_bounds__(256) void proj_gemm(
    const float* __restrict__ X, const float* __restrict__ W,
    const float* __restrict__ bias, unsigned short* __restrict__ out) {
  __shared__ float As[16][68];
  __shared__ float Bs[16][68];
  const int tid = threadIdx.x, tx = tid & 15, ty = tid >> 4;
  const int row0 = blockIdx.y * 64, col0 = blockIdx.x * 64;
  const int lr = tid >> 2, lk = (tid & 3) << 2;
  float acc[4][4] = {};
  for (int k0 = 0; k0 < C_; k0 += 16) {
    const float4 va = *(const float4*)(X + (size_t)(row0 + lr) * C_ + k0 + lk);
    const float4 vb = *(const float4*)(W + (size_t)(col0 + lr) * C_ + k0 + lk);
    As[lk + 0][lr] = va.x; As[lk + 1][lr] = va.y;
    As[lk + 2][lr] = va.z; As[lk + 3][lr] = va.w;
    Bs[lk + 0][lr] = vb.x; Bs[lk + 1][lr] = vb.y;
    Bs[lk + 2][lr] = vb.z; Bs[lk + 3][lr] = vb.w;
    __syncthreads();
#pragma unroll
    for (int k = 0; k < 16; ++k) {
      const float4 a = *(const float4*)&As[k][ty << 2];
      const float4 b = *(const float4*)&Bs[k][tx << 2];
      const float av[4] = {a.x, a.y, a.z, a.w};
      const float bv[4] = {b.x, b.y, b.z, b.w};
#pragma unroll
      for (int i = 0; i < 4; ++i)
#pragma unroll
        for (int j = 0; j < 4; ++j) acc[i][j] = fmaf(av[i], bv[j], acc[i][j]);
    }
    __syncthreads();
  }
#pragma unroll
  for (int i = 0; i < 4; ++i) {
    const int r = row0 + (ty << 2) + i;
    const int b = r >> 10, n = r & 1023;
#pragma unroll
    for (int j = 0; j < 4; ++j) {
      const int c = col0 + (tx << 2) + j;
      const int h = c >> 6, d = c & 63;
      out[(((size_t)(b * H_ + h) << 10) + n) * 64 + d] = f2bf(acc[i][j] + bias[c]);
    }
  }
}

// ---------- output GEMM: out(fp32) = X @ W^T + bias ------------------------
__global__ __launch_bounds__(256) void out_gemm(
    const float* __restrict__ X, const float* __restrict__ W,
    const float* __restrict__ bias, float* __restrict__ out) {
  __shared__ float As[16][68];
  __shared__ float Bs[16][68];
  const int tid = threadIdx.x, tx = tid & 15, ty = tid >> 4;
  const int row0 = blockIdx.y * 64, col0 = blockIdx.x * 64;
  const int lr = tid >> 2, lk = (tid & 3) << 2;
  float acc[4][4] = {};
  for (int k0 = 0; k0 < C_; k0 += 16) {
    const float4 va = *(const float4*)(X + (size_t)(row0 + lr) * C_ + k0 + lk);
    const float4 vb = *(const float4*)(W + (size_t)(col0 + lr) * C_ + k0 + lk);
    As[lk + 0][lr] = va.x; As[lk + 1][lr] = va.y;
    As[lk + 2][lr] = va.z; As[lk + 3][lr] = va.w;
    Bs[lk + 0][lr] = vb.x; Bs[lk + 1][lr] = vb.y;
    Bs[lk + 2][lr] = vb.z; Bs[lk + 3][lr] = vb.w;
    __syncthreads();
#pragma unroll
    for (int k = 0; k < 16; ++k) {
      const float4 a = *(const float4*)&As[k][ty << 2];
      const float4 b = *(const float4*)&Bs[k][tx << 2];
      const float av[4] = {a.x, a.y, a.z, a.w};
      const float bv[4] = {b.x, b.y, b.z, b.w};
#pragma unroll
      for (int i = 0; i < 4; ++i)
#pragma unroll
        for (int j = 0; j < 4; ++j) acc[i][j] = fmaf(av[i], bv[j], acc[i][j]);
    }
    __syncthreads();
  }
#pragma unroll
  for (int i = 0; i < 4; ++i) {
    const int r = row0 + (ty << 2) + i;
#pragma unroll
    for (int j = 0; j < 4; ++j) {
      const int c = col0 + (tx << 2) + j;
      out[(size_t)r * C_ + c] = acc[i][j] + bias[c];
    }
  }
}

// ---------- scores (QK^T/8) fused with 3x3 depthwise conv, per batch -------
// fp32 score output S[h][i][j], batch-local.
__global__ __launch_bounds__(256) void scores_conv(
    const unsigned short* __restrict__ Qb, const unsigned short* __restrict__ Kb,
    const float* __restrict__ cw, float* __restrict__ S, int bb) {
  __shared__ float Qs[64][68];  // [d][i]
  __shared__ float Ks[64][68];  // [d][j]
  __shared__ float Ss[64][68];  // scores [i][j]
  const int tid = threadIdx.x;
  const int h = blockIdx.z;
  const int i0 = blockIdx.y * 62, j0 = blockIdx.x * 62;
  const unsigned short* Qz = Qb + (size_t)(bb * H_ + h) * N_ * 64;
  const unsigned short* Kz = Kb + (size_t)(bb * H_ + h) * N_ * 64;
  const int r = tid >> 2, dk = (tid & 3) << 2;
#pragma unroll
  for (int p = 0; p < 4; ++p) {
    const int d = dk + (p << 4);
    const int gi = i0 - 1 + r, gj = j0 - 1 + r;
    float q0 = 0, q1 = 0, q2 = 0, q3 = 0, c0 = 0, c1 = 0, c2 = 0, c3 = 0;
    if (gi >= 0 && gi < N_) {
      const ushort4 u = *(const ushort4*)(Qz + (size_t)gi * 64 + d);
      q0 = bf2f(u.x); q1 = bf2f(u.y); q2 = bf2f(u.z); q3 = bf2f(u.w);
    }
    if (gj >= 0 && gj < N_) {
      const ushort4 u = *(const ushort4*)(Kz + (size_t)gj * 64 + d);
      c0 = bf2f(u.x); c1 = bf2f(u.y); c2 = bf2f(u.z); c3 = bf2f(u.w);
    }
    Qs[d + 0][r] = q0 * 0.125f; Qs[d + 1][r] = q1 * 0.125f;
    Qs[d + 2][r] = q2 * 0.125f; Qs[d + 3][r] = q3 * 0.125f;
    Ks[d + 0][r] = c0; Ks[d + 1][r] = c1;
    Ks[d + 2][r] = c2; Ks[d + 3][r] = c3;
  }
  __syncthreads();
  const int tx = tid & 15, ty = tid >> 4;
  float acc[4][4] = {};
#pragma unroll 8
  for (int d = 0; d < 64; ++d) {
    const float4 a = *(const float4*)&Qs[d][ty << 2];
    const float4 b = *(const float4*)&Ks[d][tx << 2];
    const float av[4] = {a.x, a.y, a.z, a.w};
    const float bv[4] = {b.x, b.y, b.z, b.w};
#pragma unroll
    for (int i = 0; i < 4; ++i)
#pragma unroll
      for (int j = 0; j < 4; ++j) acc[i][j] = fmaf(av[i], bv[j], acc[i][j]);
  }
#pragma unroll
  for (int i = 0; i < 4; ++i)
    *(float4*)&Ss[(ty << 2) + i][tx << 2] =
        make_float4(acc[i][0], acc[i][1], acc[i][2], acc[i][3]);
  __syncthreads();

  float w[9];
#pragma unroll
  for (int q = 0; q < 9; ++q) w[q] = cw[h * 9 + q];
  for (int idx = tid; idx < 62 * 62; idx += 256) {
    const int oi = idx / 62, oj = idx % 62;
    const int gi = i0 + oi, gj = j0 + oj;
    if (gi < N_ && gj < N_) {
      float s = 0.f;
#pragma unroll
      for (int a2 = 0; a2 < 3; ++a2)
#pragma unroll
        for (int c2 = 0; c2 < 3; ++c2)
          s = fmaf(Ss[oi + a2][oj + c2], w[a2 * 3 + c2], s);
      S[((size_t)h * N_ + gi) * N_ + gj] = s;
    }
  }
}

// ---------- softmax over k + cross-head mix; fp32 rows -> bf16 in-place ----
__global__ __launch_bounds__(256) void softmax_mix(
    float* __restrict__ S, const float* __restrict__ hm) {
  const int i = blockIdx.x, g = blockIdx.y, t = threadIdx.x;
  float* r0 = S + (((size_t)(2 * g) << 10) + i) * N_;
  float* r1 = S + (((size_t)(2 * g + 1) << 10) + i) * N_;
  __shared__ float s0m[4], s1m[4], s0s[4], s1s[4];
  const float4 v0 = ((const float4*)r0)[t];
  const float4 v1 = ((const float4*)r1)[t];
  float x0[4] = {v0.x, v0.y, v0.z, v0.w};
  float x1[4] = {v1.x, v1.y, v1.z, v1.w};
  float m0 = fmaxf(fmaxf(x0[0], x0[1]), fmaxf(x0[2], x0[3]));
  float m1 = fmaxf(fmaxf(x1[0], x1[1]), fmaxf(x1[2], x1[3]));
#pragma unroll
  for (int o = 32; o >= 1; o >>= 1) {
    m0 = fmaxf(m0, __shfl_xor(m0, o));
    m1 = fmaxf(m1, __shfl_xor(m1, o));
  }
  const int lane = t & 63, wv = t >> 6;
  if (lane == 0) { s0m[wv] = m0; s1m[wv] = m1; }
  __syncthreads();
  m0 = fmaxf(fmaxf(s0m[0], s0m[1]), fmaxf(s0m[2], s0m[3]));
  m1 = fmaxf(fmaxf(s1m[0], s1m[1]), fmaxf(s1m[2], s1m[3]));
  float e0[4], e1[4];
  float t0 = 0.f, t1 = 0.f;
#pragma unroll
  for (int q = 0; q < 4; ++q) {
    e0[q] = expf(x0[q] - m0); t0 += e0[q];
    e1[q] = expf(x1[q] - m1); t1 += e1[q];
  }
#pragma unroll
  for (int o = 32; o >= 1; o >>= 1) {
    t0 += __shfl_xor(t0, o);
    t1 += __shfl_xor(t1, o);
  }
  if (lane == 0) { s0s[wv] = t0; s1s[wv] = t1; }
  __syncthreads();
  t0 = s0s[0] + s0s[1] + s0s[2] + s0s[3];
  t1 = s1s[0] + s1s[1] + s1s[2] + s1s[3];
  const float inv0 = 1.f / t0, inv1 = 1.f / t1;
  const float* hm4 = hm + g * 4;
  const float m00 = hm4[0], m01 = hm4[1], m10 = hm4[2], m11 = hm4[3];
  ushort4 o0, o1;
  {
    float a0, a1;
    a0 = e0[0] * inv0; a1 = e1[0] * inv1;
    o0.x = f2bf(m00 * a0 + m10 * a1); o1.x = f2bf(m01 * a0 + m11 * a1);
    a0 = e0[1] * inv0; a1 = e1[1] * inv1;
    o0.y = f2bf(m00 * a0 + m10 * a1); o1.y = f2bf(m01 * a0 + m11 * a1);
    a0 = e0[2] * inv0; a1 = e1[2] * inv1;
    o0.z = f2bf(m00 * a0 + m10 * a1); o1.z = f2bf(m01 * a0 + m11 * a1);
    a0 = e0[3] * inv0; a1 = e1[3] * inv1;
    o0.w = f2bf(m00 * a0 + m10 * a1); o1.w = f2bf(m01 * a0 + m11 * a1);
  }
  // in-place: bf16 row over first half of the fp32 row (reads done pre-barrier)
  ((ushort4*)r0)[t] = o0;
  ((ushort4*)r1)[t] = o1;
}

// ---------- PV: pvout(b,N,C fp32) = mixed_attn(bf16) @ V(bf16) -------------
// A = ushort view of S; row (h,i) bf16 data at ushort offset (h*N+i)*2N.
__global__ __launch_bounds__(256) void pv_gemm(
    const unsigned short* __restrict__ A, const unsigned short* __restrict__ Vb,
    float* __restrict__ pvout, int bb) {
  __shared__ float As[16][68];
  __shared__ float Bs[16][68];
  const int tid = threadIdx.x;
  const int h = blockIdx.y;
  const int i0 = blockIdx.x * 64;
  const unsigned short* Az = A + (size_t)h * N_ * N_ * 2;
  const unsigned short* Vz = Vb + (size_t)(bb * H_ + h) * N_ * 64;
  const int tx = tid & 15, ty = tid >> 4;
  const int ar = tid >> 2, ak = (tid & 3) << 2;
  const int vk = tid >> 4, vd = (tid & 15) << 2;
  float acc[4][4] = {};
  for (int k0 = 0; k0 < N_; k0 += 16) {
    const ushort4 ua = *(const ushort4*)(Az + (size_t)(i0 + ar) * 2 * N_ + k0 + ak);
    const ushort4 uv = *(const ushort4*)(Vz + (size_t)(k0 + vk) * 64 + vd);
    As[ak + 0][ar] = bf2f(ua.x); As[ak + 1][ar] = bf2f(ua.y);
    As[ak + 2][ar] = bf2f(ua.z); As[ak + 3][ar] = bf2f(ua.w);
    Bs[vk][vd + 0] = bf2f(uv.x); Bs[vk][vd + 1] = bf2f(uv.y);
    Bs[vk][vd + 2] = bf2f(uv.z); Bs[vk][vd + 3] = bf2f(uv.w);
    __syncthreads();
#pragma unroll
    for (int k = 0; k < 16; ++k) {
      const float4 a = *(const float4*)&As[k][ty << 2];
      const float4 b = *(const float4*)&Bs[k][tx << 2];
      const float av[4] = {a.x, a.y, a.z, a.w};
      const float bv[4] = {b.x, b.y, b.z, b.w};
#pragma unroll
      for (int i = 0; i < 4; ++i)
#pragma unroll
        for (int j = 0; j < 4; ++j) acc[i][j] = fmaf(av[i], bv[j], acc[i][j]);
    }
    __syncthreads();
  }
#pragma unroll
  for (int i = 0; i < 4; ++i)
#pragma unroll
    for (int j = 0; j < 4; ++j)
      pvout[(size_t)(bb * N_ + i0 + (ty << 2) + i) * C_ + h * 64 + (tx << 2) + j] =
          acc[i][j];
}

extern "C" void kernel_launch(void* const* d_in, const int* in_sizes, int n_in,
                              void* d_out, int out_size, void* d_ws, size_t ws_size,
                              hipStream_t stream) {
  const float* query = (const float*)d_in[0];
  const float* key   = (const float*)d_in[1];
  const float* value = (const float*)d_in[2];
  const float* Wq = (const float*)d_in[3];
  const float* bq = (const float*)d_in[4];
  const float* Wk = (const float*)d_in[5];
  const float* bk = (const float*)d_in[6];
  const float* Wv = (const float*)d_in[7];
  const float* bv = (const float*)d_in[8];
  const float* cw = (const float*)d_in[9];
  const float* hm = (const float*)d_in[10];
  const float* Wo = (const float*)d_in[11];
  const float* bo = (const float*)d_in[12];
  float* out = (float*)d_out;

  // workspace layout (113.25 MB total)
  char* ws = (char*)d_ws;
  const size_t SZ_BF = (size_t)B_ * H_ * N_ * D_ * 2;          // 12,582,912
  unsigned short* Qb = (unsigned short*)ws;
  unsigned short* Kb = (unsigned short*)(ws + SZ_BF);
  unsigned short* Vb = (unsigned short*)(ws + 2 * SZ_BF);
  float* pvout = (float*)(ws + 3 * SZ_BF);                     // 25,165,824
  float* S = (float*)(ws + 3 * SZ_BF + (size_t)B_ * N_ * C_ * 4);  // 50,331,648

  const dim3 blk(256);
  const dim3 gproj(C_ / 64, (B_ * N_) / 64);
  proj_gemm<<<gproj, blk, 0, stream>>>(query, Wq, bq, Qb);
  proj_gemm<<<gproj, blk, 0, stream>>>(key, Wk, bk, Kb);
  proj_gemm<<<gproj, blk, 0, stream>>>(value, Wv, bv, Vb);

  for (int b = 0; b < B_; ++b) {
    scores_conv<<<dim3(17, 17, H_), blk, 0, stream>>>(Qb, Kb, cw, S, b);
    softmax_mix<<<dim3(N_, G_), blk, 0, stream>>>(S, hm);
    pv_gemm<<<dim3(N_ / 64, H_), blk, 0, stream>>>((const unsigned short*)S, Vb,
                                                   pvout, b);
  }

  out_gemm<<<gproj, blk, 0, stream>>>(pvout, Wo, bo, out);
}

// Round 3
// 604.921 us; speedup vs baseline: 2.4771x; 2.4771x over previous
//
#include <hip/hip_runtime.h>
#include <stdint.h>

#define B_ 8
#define N_ 1024
#define C_ 768
#define H_ 12
#define G_ 6

typedef __attribute__((ext_vector_type(8))) short bf16x8;
typedef __attribute__((ext_vector_type(8))) unsigned short u16x8;
typedef __attribute__((ext_vector_type(4))) float f32x4;

__device__ __forceinline__ float bf2f(unsigned short u) {
  return __uint_as_float(((unsigned)u) << 16);
}
__device__ __forceinline__ unsigned short f2bf(float f) {
  unsigned x = __float_as_uint(f);
  unsigned r = x + 0x7fffu + ((x >> 16) & 1u);  // RNE
  return (unsigned short)(r >> 16);
}

// ================= MFMA GEMM body: out = X @ W^T + bias ====================
// X [M][768] fp32, W [cols][768] fp32. 128x128 tile, BK=32, 4 waves (64x64 each).
// MODE 0: fp32 out [M][768]. MODE 1: bf16 out in (B,H,N,D) layout.
template <int MODE>
__device__ __forceinline__ void gemm_body(
    const float* __restrict__ X, const float* __restrict__ W,
    const float* __restrict__ bias, void* __restrict__ out) {
  __shared__ unsigned short As[128][40];
  __shared__ unsigned short Bs[128][40];
  const int tid = threadIdx.x;
  const int wid = tid >> 6, lane = tid & 63;
  const int lr = lane & 15, lk = (lane >> 4) << 3;
  const int row0 = blockIdx.y * 128, col0 = blockIdx.x * 128;
  const int wr = (wid & 1) << 6, wc = (wid >> 1) << 6;
  const int srow = tid >> 3, scol = (tid & 7) << 2;
  f32x4 acc[4][4] = {};
  for (int k0 = 0; k0 < C_; k0 += 32) {
#pragma unroll
    for (int it = 0; it < 4; ++it) {
      const int r = srow + (it << 5);
      const float4 va = *(const float4*)(X + (size_t)(row0 + r) * C_ + k0 + scol);
      const float4 vb = *(const float4*)(W + (size_t)(col0 + r) * C_ + k0 + scol);
      *(ushort4*)&As[r][scol] =
          make_ushort4(f2bf(va.x), f2bf(va.y), f2bf(va.z), f2bf(va.w));
      *(ushort4*)&Bs[r][scol] =
          make_ushort4(f2bf(vb.x), f2bf(vb.y), f2bf(vb.z), f2bf(vb.w));
    }
    __syncthreads();
    bf16x8 af[4], bg[4];
#pragma unroll
    for (int m = 0; m < 4; ++m) af[m] = *(const bf16x8*)&As[wr + (m << 4) + lr][lk];
#pragma unroll
    for (int n = 0; n < 4; ++n) bg[n] = *(const bf16x8*)&Bs[wc + (n << 4) + lr][lk];
#pragma unroll
    for (int m = 0; m < 4; ++m)
#pragma unroll
      for (int n = 0; n < 4; ++n)
        acc[m][n] = __builtin_amdgcn_mfma_f32_16x16x32_bf16(af[m], bg[n],
                                                            acc[m][n], 0, 0, 0);
    __syncthreads();
  }
#pragma unroll
  for (int m = 0; m < 4; ++m) {
#pragma unroll
    for (int n = 0; n < 4; ++n) {
      const int colc = col0 + wc + (n << 4) + lr;
      const float bv = bias[colc];
#pragma unroll
      for (int q = 0; q < 4; ++q) {
        const int r = row0 + wr + (m << 4) + ((lane >> 4) << 2) + q;
        const float v = acc[m][n][q] + bv;
        if (MODE == 0) {
          ((float*)out)[(size_t)r * C_ + colc] = v;
        } else {
          const int bb = r >> 10, nn = r & 1023;
          const int hh = colc >> 6, dd = colc & 63;
          ((unsigned short*)out)[(((size_t)(bb * H_ + hh) << 10) + nn) * 64 + dd] =
              f2bf(v);
        }
      }
    }
  }
}

__global__ __launch_bounds__(256) void proj3(
    const float* __restrict__ q, const float* __restrict__ k,
    const float* __restrict__ v, const float* __restrict__ Wq,
    const float* __restrict__ Wk, const float* __restrict__ Wv,
    const float* __restrict__ bq, const float* __restrict__ bk,
    const float* __restrict__ bv, unsigned short* Qb, unsigned short* Kb,
    unsigned short* Vb) {
  const float *X, *W, *bias;
  unsigned short* out;
  if (blockIdx.z == 0) { X = q; W = Wq; bias = bq; out = Qb; }
  else if (blockIdx.z == 1) { X = k; W = Wk; bias = bk; out = Kb; }
  else { X = v; W = Wv; bias = bv; out = Vb; }
  gemm_body<1>(X, W, bias, out);
}

__global__ __launch_bounds__(256) void oproj(
    const float* __restrict__ X, const float* __restrict__ Wo,
    const float* __restrict__ bo, float* __restrict__ out) {
  gemm_body<0>(X, Wo, bo, out);
}

// ========= scores (QK^T/8, MFMA) fused with 3x3 depthwise conv =============
// 64x64 score tile (rows i0-1..i0+62), conv output 62x62, fp32 S out.
__global__ __launch_bounds__(256) void scores_conv(
    const unsigned short* __restrict__ Qb, const unsigned short* __restrict__ Kb,
    const float* __restrict__ cw, float* __restrict__ S, int bb) {
  __shared__ unsigned short Qs[64][72];  // [i][d]
  __shared__ unsigned short Ks[64][72];  // [j][d]
  __shared__ float Ss[64][68];           // scores [i][j]
  const int tid = threadIdx.x;
  const int wid = tid >> 6, lane = tid & 63;
  const int lr = lane & 15, lk = (lane >> 4) << 3;
  const int h = blockIdx.z;
  const int i0 = blockIdx.y * 62, j0 = blockIdx.x * 62;
  const unsigned short* Qz = Qb + (size_t)(bb * H_ + h) * N_ * 64;
  const unsigned short* Kz = Kb + (size_t)(bb * H_ + h) * N_ * 64;
  // stage 64 rows x 64 d (halo rows zero-filled)
  {
    const int r = tid >> 2, dbase = (tid & 3) << 4;
    const int gi = i0 - 1 + r, gj = j0 - 1 + r;
    u16x8 q0 = 0, q1 = 0, c0 = 0, c1 = 0;
    if (gi >= 0 && gi < N_) {
      q0 = *(const u16x8*)(Qz + (size_t)gi * 64 + dbase);
      q1 = *(const u16x8*)(Qz + (size_t)gi * 64 + dbase + 8);
    }
    if (gj >= 0 && gj < N_) {
      c0 = *(const u16x8*)(Kz + (size_t)gj * 64 + dbase);
      c1 = *(const u16x8*)(Kz + (size_t)gj * 64 + dbase + 8);
    }
    *(u16x8*)&Qs[r][dbase] = q0;
    *(u16x8*)&Qs[r][dbase + 8] = q1;
    *(u16x8*)&Ks[r][dbase] = c0;
    *(u16x8*)&Ks[r][dbase + 8] = c1;
  }
  __syncthreads();
  // QK^T: 4 waves, each 32x32 quadrant
  const int wr = (wid & 1) << 5, wc = (wid >> 1) << 5;
  f32x4 acc[2][2] = {};
#pragma unroll
  for (int d0 = 0; d0 < 64; d0 += 32) {
    bf16x8 af[2], bg[2];
#pragma unroll
    for (int m = 0; m < 2; ++m)
      af[m] = *(const bf16x8*)&Qs[wr + (m << 4) + lr][d0 + lk];
#pragma unroll
    for (int n = 0; n < 2; ++n)
      bg[n] = *(const bf16x8*)&Ks[wc + (n << 4) + lr][d0 + lk];
#pragma unroll
    for (int m = 0; m < 2; ++m)
#pragma unroll
      for (int n = 0; n < 2; ++n)
        acc[m][n] = __builtin_amdgcn_mfma_f32_16x16x32_bf16(af[m], bg[n],
                                                            acc[m][n], 0, 0, 0);
  }
#pragma unroll
  for (int m = 0; m < 2; ++m)
#pragma unroll
    for (int n = 0; n < 2; ++n)
#pragma unroll
      for (int q = 0; q < 4; ++q)
        Ss[wr + (m << 4) + ((lane >> 4) << 2) + q][wc + (n << 4) + lr] =
            acc[m][n][q] * 0.125f;
  __syncthreads();
  // 3x3 depthwise conv -> fp32 S
  float w[9];
#pragma unroll
  for (int q = 0; q < 9; ++q) w[q] = cw[h * 9 + q];
  for (int idx = tid; idx < 62 * 62; idx += 256) {
    const int oi = idx / 62, oj = idx % 62;
    const int gi = i0 + oi, gj = j0 + oj;
    if (gi < N_ && gj < N_) {
      float s = 0.f;
#pragma unroll
      for (int a2 = 0; a2 < 3; ++a2)
#pragma unroll
        for (int c2 = 0; c2 < 3; ++c2)
          s = fmaf(Ss[oi + a2][oj + c2], w[a2 * 3 + c2], s);
      S[((size_t)h * N_ + gi) * N_ + gj] = s;
    }
  }
}

// ---------- softmax over k + cross-head mix; fp32 rows -> bf16 in-place ----
__global__ __launch_bounds__(256) void softmax_mix(
    float* __restrict__ S, const float* __restrict__ hm) {
  const int i = blockIdx.x, g = blockIdx.y, t = threadIdx.x;
  float* r0 = S + (((size_t)(2 * g) << 10) + i) * N_;
  float* r1 = S + (((size_t)(2 * g + 1) << 10) + i) * N_;
  __shared__ float s0m[4], s1m[4], s0s[4], s1s[4];
  const float4 v0 = ((const float4*)r0)[t];
  const float4 v1 = ((const float4*)r1)[t];
  float x0[4] = {v0.x, v0.y, v0.z, v0.w};
  float x1[4] = {v1.x, v1.y, v1.z, v1.w};
  float m0 = fmaxf(fmaxf(x0[0], x0[1]), fmaxf(x0[2], x0[3]));
  float m1 = fmaxf(fmaxf(x1[0], x1[1]), fmaxf(x1[2], x1[3]));
#pragma unroll
  for (int o = 32; o >= 1; o >>= 1) {
    m0 = fmaxf(m0, __shfl_xor(m0, o));
    m1 = fmaxf(m1, __shfl_xor(m1, o));
  }
  const int lane = t & 63, wv = t >> 6;
  if (lane == 0) { s0m[wv] = m0; s1m[wv] = m1; }
  __syncthreads();
  m0 = fmaxf(fmaxf(s0m[0], s0m[1]), fmaxf(s0m[2], s0m[3]));
  m1 = fmaxf(fmaxf(s1m[0], s1m[1]), fmaxf(s1m[2], s1m[3]));
  float e0[4], e1[4];
  float t0 = 0.f, t1 = 0.f;
#pragma unroll
  for (int q = 0; q < 4; ++q) {
    e0[q] = expf(x0[q] - m0); t0 += e0[q];
    e1[q] = expf(x1[q] - m1); t1 += e1[q];
  }
#pragma unroll
  for (int o = 32; o >= 1; o >>= 1) {
    t0 += __shfl_xor(t0, o);
    t1 += __shfl_xor(t1, o);
  }
  if (lane == 0) { s0s[wv] = t0; s1s[wv] = t1; }
  __syncthreads();
  t0 = s0s[0] + s0s[1] + s0s[2] + s0s[3];
  t1 = s1s[0] + s1s[1] + s1s[2] + s1s[3];
  const float inv0 = 1.f / t0, inv1 = 1.f / t1;
  const float* hm4 = hm + g * 4;
  const float m00 = hm4[0], m01 = hm4[1], m10 = hm4[2], m11 = hm4[3];
  ushort4 o0, o1;
  {
    float a0, a1;
    a0 = e0[0] * inv0; a1 = e1[0] * inv1;
    o0.x = f2bf(m00 * a0 + m10 * a1); o1.x = f2bf(m01 * a0 + m11 * a1);
    a0 = e0[1] * inv0; a1 = e1[1] * inv1;
    o0.y = f2bf(m00 * a0 + m10 * a1); o1.y = f2bf(m01 * a0 + m11 * a1);
    a0 = e0[2] * inv0; a1 = e1[2] * inv1;
    o0.z = f2bf(m00 * a0 + m10 * a1); o1.z = f2bf(m01 * a0 + m11 * a1);
    a0 = e0[3] * inv0; a1 = e1[3] * inv1;
    o0.w = f2bf(m00 * a0 + m10 * a1); o1.w = f2bf(m01 * a0 + m11 * a1);
  }
  ((ushort4*)r0)[t] = o0;
  ((ushort4*)r1)[t] = o1;
}

// ---------- PV (MFMA): pvout(b,N,C fp32) = mixed_attn(bf16) @ V(bf16) ------
// 128 rows x 64 d per block, BK=32. A rows at ushort pitch 2N in S.
__global__ __launch_bounds__(256) void pv_gemm(
    const unsigned short* __restrict__ A, const unsigned short* __restrict__ Vb,
    float* __restrict__ pvout, int bb) {
  __shared__ unsigned short As2[128][40];  // [i][k]
  __shared__ unsigned short Vs[64][40];    // [d][k] (transposed V)
  const int tid = threadIdx.x;
  const int wid = tid >> 6, lane = tid & 63;
  const int lr = lane & 15, lk = (lane >> 4) << 3;
  const int h = blockIdx.y;
  const int i0 = blockIdx.x * 128;
  const unsigned short* Az = A + (size_t)h * N_ * 2 * N_;
  const unsigned short* Vz = Vb + (size_t)(bb * H_ + h) * N_ * 64;
  const int wr = wid << 5;
  const int ar = tid >> 1, akb = (tid & 1) << 4;
  const int vc = tid & 63, vkc = (tid >> 6) << 3;
  f32x4 acc[2][4] = {};
  for (int k0 = 0; k0 < N_; k0 += 32) {
    const u16x8 a0 = *(const u16x8*)(Az + (size_t)(i0 + ar) * 2 * N_ + k0 + akb);
    const u16x8 a1 = *(const u16x8*)(Az + (size_t)(i0 + ar) * 2 * N_ + k0 + akb + 8);
    *(u16x8*)&As2[ar][akb] = a0;
    *(u16x8*)&As2[ar][akb + 8] = a1;
    u16x8 vv;
#pragma unroll
    for (int q2 = 0; q2 < 8; ++q2)
      vv[q2] = Vz[(size_t)(k0 + vkc + q2) * 64 + vc];
    *(u16x8*)&Vs[vc][vkc] = vv;
    __syncthreads();
    bf16x8 af[2], bg[4];
#pragma unroll
    for (int m = 0; m < 2; ++m)
      af[m] = *(const bf16x8*)&As2[wr + (m << 4) + lr][lk];
#pragma unroll
    for (int n = 0; n < 4; ++n)
      bg[n] = *(const bf16x8*)&Vs[(n << 4) + lr][lk];
#pragma unroll
    for (int m = 0; m < 2; ++m)
#pragma unroll
      for (int n = 0; n < 4; ++n)
        acc[m][n] = __builtin_amdgcn_mfma_f32_16x16x32_bf16(af[m], bg[n],
                                                            acc[m][n], 0, 0, 0);
    __syncthreads();
  }
#pragma unroll
  for (int m = 0; m < 2; ++m)
#pragma unroll
    for (int n = 0; n < 4; ++n)
#pragma unroll
      for (int q = 0; q < 4; ++q) {
        const int r = i0 + wr + (m << 4) + ((lane >> 4) << 2) + q;
        pvout[(size_t)(bb * N_ + r) * C_ + h * 64 + (n << 4) + lr] = acc[m][n][q];
      }
}

extern "C" void kernel_launch(void* const* d_in, const int* in_sizes, int n_in,
                              void* d_out, int out_size, void* d_ws, size_t ws_size,
                              hipStream_t stream) {
  const float* query = (const float*)d_in[0];
  const float* key   = (const float*)d_in[1];
  const float* value = (const float*)d_in[2];
  const float* Wq = (const float*)d_in[3];
  const float* bq = (const float*)d_in[4];
  const float* Wk = (const float*)d_in[5];
  const float* bk = (const float*)d_in[6];
  const float* Wv = (const float*)d_in[7];
  const float* bv = (const float*)d_in[8];
  const float* cw = (const float*)d_in[9];
  const float* hm = (const float*)d_in[10];
  const float* Wo = (const float*)d_in[11];
  const float* bo = (const float*)d_in[12];
  float* out = (float*)d_out;

  // workspace layout (113.25 MB total)
  char* ws = (char*)d_ws;
  const size_t SZ_BF = (size_t)B_ * H_ * N_ * 64 * 2;  // 12,582,912
  unsigned short* Qb = (unsigned short*)ws;
  unsigned short* Kb = (unsigned short*)(ws + SZ_BF);
  unsigned short* Vb = (unsigned short*)(ws + 2 * SZ_BF);
  float* pvout = (float*)(ws + 3 * SZ_BF);                          // 25 MB
  float* S = (float*)(ws + 3 * SZ_BF + (size_t)B_ * N_ * C_ * 4);   // 50 MB

  const dim3 blk(256);
  proj3<<<dim3(6, 64, 3), blk, 0, stream>>>(query, key, value, Wq, Wk, Wv, bq, bk,
                                            bv, Qb, Kb, Vb);
  for (int b = 0; b < B_; ++b) {
    scores_conv<<<dim3(17, 17, H_), blk, 0, stream>>>(Qb, Kb, cw, S, b);
    softmax_mix<<<dim3(N_, G_), blk, 0, stream>>>(S, hm);
    pv_gemm<<<dim3(N_ / 128, H_), blk, 0, stream>>>((const unsigned short*)S, Vb,
                                                    pvout, b);
  }
  oproj<<<dim3(6, 64), blk, 0, stream>>>(pvout, Wo, bo, out);
}

// Round 4
// 367.933 us; speedup vs baseline: 4.0726x; 1.6441x over previous
//
#include <hip/hip_runtime.h>
#include <stdint.h>

#define B_ 8
#define N_ 1024
#define C_ 768
#define H_ 12
#define G_ 6
#define QBLK 30
#define KSTEP 62
#define NQT 35  // ceil(1024/30)
#define NKS 17  // ceil(1024/62)

typedef __attribute__((ext_vector_type(8))) short bf16x8;
typedef __attribute__((ext_vector_type(8))) unsigned short u16x8;
typedef __attribute__((ext_vector_type(4))) float f32x4;

__device__ __forceinline__ float bf2f(unsigned short u) {
  return __uint_as_float(((unsigned)u) << 16);
}
__device__ __forceinline__ unsigned short f2bf(float f) {
  unsigned x = __float_as_uint(f);
  unsigned r = x + 0x7fffu + ((x >> 16) & 1u);  // RNE
  return (unsigned short)(r >> 16);
}

// ================= MFMA GEMM body: out = X @ W^T + bias ====================
// 128x128 tile, BK=32, 4 waves. MODE 0: fp32 [M][768]. MODE 1: bf16 (B,H,N,D).
template <int MODE>
__device__ __forceinline__ void gemm_body(
    const float* __restrict__ X, const float* __restrict__ W,
    const float* __restrict__ bias, void* __restrict__ out,
    int row0, int col0) {
  __shared__ __align__(16) unsigned short As[128][40];
  __shared__ __align__(16) unsigned short Bs[128][40];
  const int tid = threadIdx.x;
  const int wid = tid >> 6, lane = tid & 63;
  const int lr = lane & 15, lk = (lane >> 4) << 3;
  const int wr = (wid & 1) << 6, wc = (wid >> 1) << 6;
  const int srow = tid >> 3, scol = (tid & 7) << 2;
  f32x4 acc[4][4] = {};
  for (int k0 = 0; k0 < C_; k0 += 32) {
#pragma unroll
    for (int it = 0; it < 4; ++it) {
      const int r = srow + (it << 5);
      const float4 va = *(const float4*)(X + (size_t)(row0 + r) * C_ + k0 + scol);
      const float4 vb = *(const float4*)(W + (size_t)(col0 + r) * C_ + k0 + scol);
      *(ushort4*)&As[r][scol] =
          make_ushort4(f2bf(va.x), f2bf(va.y), f2bf(va.z), f2bf(va.w));
      *(ushort4*)&Bs[r][scol] =
          make_ushort4(f2bf(vb.x), f2bf(vb.y), f2bf(vb.z), f2bf(vb.w));
    }
    __syncthreads();
    bf16x8 af[4], bg[4];
#pragma unroll
    for (int m = 0; m < 4; ++m) af[m] = *(const bf16x8*)&As[wr + (m << 4) + lr][lk];
#pragma unroll
    for (int n = 0; n < 4; ++n) bg[n] = *(const bf16x8*)&Bs[wc + (n << 4) + lr][lk];
#pragma unroll
    for (int m = 0; m < 4; ++m)
#pragma unroll
      for (int n = 0; n < 4; ++n)
        acc[m][n] = __builtin_amdgcn_mfma_f32_16x16x32_bf16(af[m], bg[n],
                                                            acc[m][n], 0, 0, 0);
    __syncthreads();
  }
#pragma unroll
  for (int m = 0; m < 4; ++m) {
#pragma unroll
    for (int n = 0; n < 4; ++n) {
      const int colc = col0 + wc + (n << 4) + lr;
      const float bv = bias[colc];
#pragma unroll
      for (int q = 0; q < 4; ++q) {
        const int r = row0 + wr + (m << 4) + ((lane >> 4) << 2) + q;
        const float v = acc[m][n][q] + bv;
        if (MODE == 0) {
          ((float*)out)[(size_t)r * C_ + colc] = v;
        } else {
          const int bb = r >> 10, nn = r & 1023;
          const int hh = colc >> 6, dd = colc & 63;
          ((unsigned short*)out)[(((size_t)(bb * H_ + hh) << 10) + nn) * 64 + dd] =
              f2bf(v);
        }
      }
    }
  }
}

__global__ __launch_bounds__(256) void proj3(
    const float* __restrict__ q, const float* __restrict__ k,
    const float* __restrict__ v, const float* __restrict__ Wq,
    const float* __restrict__ Wk, const float* __restrict__ Wv,
    const float* __restrict__ bq, const float* __restrict__ bk,
    const float* __restrict__ bv, unsigned short* Qb, unsigned short* Kb,
    unsigned short* Vb) {
  // XCD swizzle: 1152 blocks, 144/XCD contiguous (x fastest -> X-row reuse)
  const int wg = blockIdx.x;
  const int nid = (wg & 7) * 144 + (wg >> 3);
  const int x = nid % 6, y = (nid / 6) & 63, z = nid / 384;
  const float *X, *W, *bias;
  unsigned short* out;
  if (z == 0) { X = q; W = Wq; bias = bq; out = Qb; }
  else if (z == 1) { X = k; W = Wk; bias = bk; out = Kb; }
  else { X = v; W = Wv; bias = bv; out = Vb; }
  gemm_body<1>(X, W, bias, out, y << 7, x << 7);
}

__global__ __launch_bounds__(256) void oproj(
    const float* __restrict__ X, const float* __restrict__ Wo,
    const float* __restrict__ bo, float* __restrict__ out) {
  const int wg = blockIdx.x;
  const int nid = (wg & 7) * 48 + (wg >> 3);
  const int x = nid % 6, y = nid / 6;
  gemm_body<0>(X, Wo, bo, out, y << 7, x << 7);
}

// ============ fused: QK^T/8 -> 3x3 conv -> online softmax -> mix -> PV =====
// One block per (b, group, 30-row q-tile). 17 kv-steps of 62 cols.
// raw tile 32x64 covers rows i0-1..i0+30, cols j0-1..j0+62 (OOB = 0).
__global__ __launch_bounds__(256, 2) void fused_attn(
    const unsigned short* __restrict__ Qb, const unsigned short* __restrict__ Kb,
    const unsigned short* __restrict__ Vb, const float* __restrict__ cw,
    const float* __restrict__ hm, float* __restrict__ pvout) {
  __shared__ __align__(16) unsigned short Qs[2][32][72];
  __shared__ __align__(16) unsigned short Ks[2][64][72];
  __shared__ __align__(16) unsigned short Vs[2][64][72];  // [h][d][j]
  __shared__ __align__(16) float raw[2][32][68];          // aliased by Pt (bf16)
  __shared__ float msum[2][32], lsum[2][32], alf[2][32];

  const int wg = blockIdx.x;                 // 1680 = 8 * 210
  const int nid = (wg & 7) * 210 + (wg >> 3);
  const int qt = nid % NQT;
  const int bg = nid / NQT;
  const int g = bg % G_, bb = bg / G_;
  const int i0 = qt * QBLK;

  const int tid = threadIdx.x;
  const int wid = tid >> 6, lane = tid & 63;
  const int lr = lane & 15, lk = (lane >> 4) << 3;
  const int qrow = (lane >> 4) << 2;  // C-frag row base

  const size_t HSTR = (size_t)N_ * 64;
  const unsigned short* Qz = Qb + (size_t)(bb * H_ + 2 * g) * HSTR;
  const unsigned short* Kz = Kb + (size_t)(bb * H_ + 2 * g) * HSTR;
  const unsigned short* Vz = Vb + (size_t)(bb * H_ + 2 * g) * HSTR;

  if (tid < 64) {
    const int h = tid >> 5, r = tid & 31;
    msum[h][r] = -3.0e38f; lsum[h][r] = 0.f; alf[h][r] = 1.f;
  }

  // stage Q once (scaled by 1/8; OOB rows -> 0)
  {
    const int r = tid >> 3, d0 = (tid & 7) << 3;
    const int gi = i0 - 1 + r;
#pragma unroll
    for (int h = 0; h < 2; ++h) {
      u16x8 qv = {};
      if (gi >= 0 && gi < N_)
        qv = *(const u16x8*)(Qz + h * HSTR + (size_t)gi * 64 + d0);
#pragma unroll
      for (int e = 0; e < 8; ++e) qv[e] = f2bf(bf2f(qv[e]) * 0.125f);
      *(u16x8*)&Qs[h][r][d0] = qv;
    }
  }

  // conv role (fixed per thread): head ch, row cri, col-quarter cc4
  const int ch = tid >> 7;
  const int cri = (tid >> 2) & 31;
  const int cc4 = tid & 3;
  const int cbase = cc4 << 4;
  float w9[9];
#pragma unroll
  for (int q = 0; q < 9; ++q) w9[q] = cw[(2 * g + ch) * 9 + q];

  // QK role: wave -> (head, M-tile); PV role: wave -> (h, k) pair
  const int qkh = wid >> 1, qkmt = wid & 1;
  const int pvh = wid >> 1, pvk = wid & 1;
  f32x4 acc[2][4] = {};  // A_{pvh,pvk}: [mt][nt]

  for (int s = 0; s < NKS; ++s) {
    const int j0 = s * KSTEP;
    // stage K rows j0-1 .. j0+62
    {
      const int r = tid >> 2, d0 = (tid & 3) << 4;
      const int gj = j0 - 1 + r;
#pragma unroll
      for (int h = 0; h < 2; ++h) {
        u16x8 a = {}, b = {};
        if (gj >= 0 && gj < N_) {
          a = *(const u16x8*)(Kz + h * HSTR + (size_t)gj * 64 + d0);
          b = *(const u16x8*)(Kz + h * HSTR + (size_t)gj * 64 + d0 + 8);
        }
        *(u16x8*)&Ks[h][r][d0] = a;
        *(u16x8*)&Ks[h][r][d0 + 8] = b;
      }
    }
    // stage V transposed: Vs[h][d][c], c <-> global row j0+c
    {
      const int d = tid & 63, c0 = (tid >> 6) << 4;
#pragma unroll
      for (int h = 0; h < 2; ++h) {
        u16x8 va = {}, vb = {};
#pragma unroll
        for (int c = 0; c < 8; ++c) {
          const int gj0 = j0 + c0 + c, gj1 = j0 + c0 + 8 + c;
          va[c] = (gj0 < N_) ? Vz[h * HSTR + (size_t)gj0 * 64 + d] : (unsigned short)0;
          vb[c] = (gj1 < N_) ? Vz[h * HSTR + (size_t)gj1 * 64 + d] : (unsigned short)0;
        }
        *(u16x8*)&Vs[h][d][c0] = va;
        *(u16x8*)&Vs[h][d][c0 + 8] = vb;
      }
    }
    __syncthreads();

    // QK^T -> raw (each wave: one head, one 16-row M-tile, all 64 cols)
    {
      f32x4 racc[4] = {};
#pragma unroll
      for (int d0 = 0; d0 < 64; d0 += 32) {
        const bf16x8 af = *(const bf16x8*)&Qs[qkh][(qkmt << 4) + lr][d0 + lk];
#pragma unroll
        for (int nt = 0; nt < 4; ++nt) {
          const bf16x8 bg = *(const bf16x8*)&Ks[qkh][(nt << 4) + lr][d0 + lk];
          racc[nt] =
              __builtin_amdgcn_mfma_f32_16x16x32_bf16(af, bg, racc[nt], 0, 0, 0);
        }
      }
#pragma unroll
      for (int nt = 0; nt < 4; ++nt)
#pragma unroll
        for (int q = 0; q < 4; ++q)
          raw[qkh][(qkmt << 4) + qrow + q][(nt << 4) + lr] = racc[nt][q];
    }
    __syncthreads();

    // 3x3 conv + online softmax (P in regs)
    float P[16];
#pragma unroll
    for (int c = 0; c < 16; ++c) P[c] = 0.f;
    {
      const bool rvalid = (cri < QBLK) && (i0 + cri < N_);
      float pmax = -3.0e38f;
      if (rvalid) {
#pragma unroll
        for (int a2 = 0; a2 < 3; ++a2) {
          float rowv[20];
#pragma unroll
          for (int q4 = 0; q4 < 5; ++q4) {
            const float4 v = *(const float4*)&raw[ch][cri + a2][cbase + (q4 << 2)];
            rowv[q4 * 4 + 0] = v.x; rowv[q4 * 4 + 1] = v.y;
            rowv[q4 * 4 + 2] = v.z; rowv[q4 * 4 + 3] = v.w;
          }
          const float w0 = w9[a2 * 3], w1 = w9[a2 * 3 + 1], w2 = w9[a2 * 3 + 2];
#pragma unroll
          for (int c = 0; c < 16; ++c)
            P[c] = fmaf(rowv[c], w0, fmaf(rowv[c + 1], w1, fmaf(rowv[c + 2], w2, P[c])));
        }
#pragma unroll
        for (int c = 0; c < 16; ++c)
          if ((cbase + c < KSTEP) && (j0 + cbase + c < N_)) pmax = fmaxf(pmax, P[c]);
      }
      pmax = fmaxf(pmax, __shfl_xor(pmax, 1));
      pmax = fmaxf(pmax, __shfl_xor(pmax, 2));
      if (rvalid) {  // uniform across the 4-lane row group
        const float m_old = msum[ch][cri];
        const float m_new = fmaxf(m_old, pmax);
        const float a = __expf(m_old - m_new);
        float rs = 0.f;
#pragma unroll
        for (int c = 0; c < 16; ++c) {
          const bool cv = (cbase + c < KSTEP) && (j0 + cbase + c < N_);
          const float pv = cv ? __expf(P[c] - m_new) : 0.f;
          P[c] = pv; rs += pv;
        }
        rs += __shfl_xor(rs, 1);
        rs += __shfl_xor(rs, 2);
        if (cc4 == 0) {
          msum[ch][cri] = m_new;
          lsum[ch][cri] = lsum[ch][cri] * a + rs;
          alf[ch][cri] = a;
        }
      } else {
#pragma unroll
        for (int c = 0; c < 16; ++c) P[c] = 0.f;
      }
    }
    __syncthreads();  // all raw reads done

    // write P~ as bf16 into Pt (aliases raw): [2][32][72]
    {
      unsigned short* Pt = (unsigned short*)&raw[0][0][0];
      u16x8 pa, pb;
#pragma unroll
      for (int e = 0; e < 8; ++e) { pa[e] = f2bf(P[e]); pb[e] = f2bf(P[8 + e]); }
      unsigned short* dst = Pt + ((size_t)(ch * 32 + cri) * 72 + cbase);
      *(u16x8*)dst = pa;
      *(u16x8*)(dst + 8) = pb;
    }
    __syncthreads();

    // PV: acc_{h,k} = acc*alpha + P~_h @ V_k
    {
      const unsigned short* Pt = (const unsigned short*)&raw[0][0][0];
#pragma unroll
      for (int mt = 0; mt < 2; ++mt)
#pragma unroll
        for (int q = 0; q < 4; ++q) {
          const float a = alf[pvh][(mt << 4) + qrow + q];
#pragma unroll
          for (int nt = 0; nt < 4; ++nt) acc[mt][nt][q] *= a;
        }
#pragma unroll
      for (int kj = 0; kj < 64; kj += 32) {
        bf16x8 af[2];
#pragma unroll
        for (int mt = 0; mt < 2; ++mt)
          af[mt] = *(const bf16x8*)(Pt + (size_t)(pvh * 32 + (mt << 4) + lr) * 72 +
                                    kj + lk);
#pragma unroll
        for (int nt = 0; nt < 4; ++nt) {
          const bf16x8 bv = *(const bf16x8*)&Vs[pvk][(nt << 4) + lr][kj + lk];
#pragma unroll
          for (int mt = 0; mt < 2; ++mt)
            acc[mt][nt] = __builtin_amdgcn_mfma_f32_16x16x32_bf16(af[mt], bv,
                                                                  acc[mt][nt], 0, 0, 0);
        }
      }
    }
    __syncthreads();  // protect Ks/Vs/raw for next staging
  }

  // epilogue: O_k = hm[0,k]/l_0 * A_0k + hm[1,k]/l_1 * A_1k
  const float mixw = hm[(g * 2 + pvh) * 2 + pvk];
  float* Os = (float*)&Ks[0][0][0];  // [2][32][68]
  if (wid >= 2) {
#pragma unroll
    for (int mt = 0; mt < 2; ++mt)
#pragma unroll
      for (int q = 0; q < 4; ++q) {
        const int row = (mt << 4) + qrow + q;
        const float f = mixw / lsum[1][row];
#pragma unroll
        for (int nt = 0; nt < 4; ++nt)
          Os[(size_t)(pvk * 32 + row) * 68 + (nt << 4) + lr] = acc[mt][nt][q] * f;
      }
  }
  __syncthreads();
  if (wid < 2) {
#pragma unroll
    for (int mt = 0; mt < 2; ++mt)
#pragma unroll
      for (int q = 0; q < 4; ++q) {
        const int row = (mt << 4) + qrow + q;
        const int gi = i0 + row;
        if (row < QBLK && gi < N_) {
          const float f = mixw / lsum[0][row];
#pragma unroll
          for (int nt = 0; nt < 4; ++nt) {
            const float v =
                acc[mt][nt][q] * f + Os[(size_t)(pvk * 32 + row) * 68 + (nt << 4) + lr];
            pvout[(size_t)(bb * N_ + gi) * C_ + (2 * g + pvk) * 64 + (nt << 4) + lr] = v;
          }
        }
      }
  }
}

extern "C" void kernel_launch(void* const* d_in, const int* in_sizes, int n_in,
                              void* d_out, int out_size, void* d_ws, size_t ws_size,
                              hipStream_t stream) {
  const float* query = (const float*)d_in[0];
  const float* key   = (const float*)d_in[1];
  const float* value = (const float*)d_in[2];
  const float* Wq = (const float*)d_in[3];
  const float* bq = (const float*)d_in[4];
  const float* Wk = (const float*)d_in[5];
  const float* bk = (const float*)d_in[6];
  const float* Wv = (const float*)d_in[7];
  const float* bv = (const float*)d_in[8];
  const float* cw = (const float*)d_in[9];
  const float* hm = (const float*)d_in[10];
  const float* Wo = (const float*)d_in[11];
  const float* bo = (const float*)d_in[12];
  float* out = (float*)d_out;

  char* ws = (char*)d_ws;
  const size_t SZ_BF = (size_t)B_ * H_ * N_ * 64 * 2;  // 12,582,912 B
  unsigned short* Qb = (unsigned short*)ws;
  unsigned short* Kb = (unsigned short*)(ws + SZ_BF);
  unsigned short* Vb = (unsigned short*)(ws + 2 * SZ_BF);
  float* pvout = (float*)(ws + 3 * SZ_BF);  // 25,165,824 B

  const dim3 blk(256);
  proj3<<<dim3(1152), blk, 0, stream>>>(query, key, value, Wq, Wk, Wv, bq, bk, bv,
                                        Qb, Kb, Vb);
  fused_attn<<<dim3(1680), blk, 0, stream>>>(Qb, Kb, Vb, cw, hm, pvout);
  oproj<<<dim3(384), blk, 0, stream>>>(pvout, Wo, bo, out);
}

// Round 5
// 341.172 us; speedup vs baseline: 4.3920x; 1.0784x over previous
//
#include <hip/hip_runtime.h>
#include <stdint.h>

#define B_ 8
#define N_ 1024
#define C_ 768
#define H_ 12
#define G_ 6
#define QBLK 30
#define KSTEP 56
#define NQT 35  // ceil(1024/30)
#define NKS 19  // ceil(1024/56)

typedef __attribute__((ext_vector_type(8))) short bf16x8;
typedef __attribute__((ext_vector_type(8))) unsigned short u16x8;
typedef __attribute__((ext_vector_type(4))) float f32x4;

__device__ __forceinline__ float bf2f(unsigned short u) {
  return __uint_as_float(((unsigned)u) << 16);
}
__device__ __forceinline__ unsigned short f2bf(float f) {
  unsigned x = __float_as_uint(f);
  unsigned r = x + 0x7fffu + ((x >> 16) & 1u);  // RNE
  return (unsigned short)(r >> 16);
}

// ================= MFMA GEMM body: out = X @ W^T + bias ====================
// 128x128 tile, BK=32, 4 waves.
// MODE 0: fp32 out [M][768]. MODE 1: bf16 (B,H,N,D). MODE 2: bf16 (B,H,D,N).
template <int MODE>
__device__ __forceinline__ void gemm_body(
    const float* __restrict__ X, const float* __restrict__ W,
    const float* __restrict__ bias, void* __restrict__ out,
    int row0, int col0) {
  __shared__ __align__(16) unsigned short As[128][40];
  __shared__ __align__(16) unsigned short Bs[128][40];
  const int tid = threadIdx.x;
  const int wid = tid >> 6, lane = tid & 63;
  const int lr = lane & 15, lk = (lane >> 4) << 3;
  const int qrow = (lane >> 4) << 2;
  const int wr = (wid & 1) << 6, wc = (wid >> 1) << 6;
  const int srow = tid >> 3, scol = (tid & 7) << 2;
  f32x4 acc[4][4] = {};
  for (int k0 = 0; k0 < C_; k0 += 32) {
#pragma unroll
    for (int it = 0; it < 4; ++it) {
      const int r = srow + (it << 5);
      const float4 va = *(const float4*)(X + (size_t)(row0 + r) * C_ + k0 + scol);
      const float4 vb = *(const float4*)(W + (size_t)(col0 + r) * C_ + k0 + scol);
      *(ushort4*)&As[r][scol] =
          make_ushort4(f2bf(va.x), f2bf(va.y), f2bf(va.z), f2bf(va.w));
      *(ushort4*)&Bs[r][scol] =
          make_ushort4(f2bf(vb.x), f2bf(vb.y), f2bf(vb.z), f2bf(vb.w));
    }
    __syncthreads();
    bf16x8 af[4], bg[4];
#pragma unroll
    for (int m = 0; m < 4; ++m) af[m] = *(const bf16x8*)&As[wr + (m << 4) + lr][lk];
#pragma unroll
    for (int n = 0; n < 4; ++n) bg[n] = *(const bf16x8*)&Bs[wc + (n << 4) + lr][lk];
#pragma unroll
    for (int m = 0; m < 4; ++m)
#pragma unroll
      for (int n = 0; n < 4; ++n)
        acc[m][n] = __builtin_amdgcn_mfma_f32_16x16x32_bf16(af[m], bg[n],
                                                            acc[m][n], 0, 0, 0);
    __syncthreads();
  }
#pragma unroll
  for (int m = 0; m < 4; ++m) {
#pragma unroll
    for (int n = 0; n < 4; ++n) {
      const int colc = col0 + wc + (n << 4) + lr;
      const float bv = bias[colc];
      if (MODE == 2) {
        // V^T: pack 4 consecutive rows (q) -> n-contiguous ushort4 store
        const int r0 = row0 + wr + (m << 4) + qrow;
        const int bb = r0 >> 10, nn0 = r0 & 1023;
        const int hh = colc >> 6, dd = colc & 63;
        ushort4 pk;
        pk.x = f2bf(acc[m][n][0] + bv);
        pk.y = f2bf(acc[m][n][1] + bv);
        pk.z = f2bf(acc[m][n][2] + bv);
        pk.w = f2bf(acc[m][n][3] + bv);
        *(ushort4*)&((unsigned short*)out)[(((size_t)(bb * H_ + hh) << 6) + dd)
                                               * 1024 + nn0] = pk;
      } else {
#pragma unroll
        for (int q = 0; q < 4; ++q) {
          const int r = row0 + wr + (m << 4) + qrow + q;
          const float v = acc[m][n][q] + bv;
          if (MODE == 0) {
            ((float*)out)[(size_t)r * C_ + colc] = v;
          } else {
            const int bb = r >> 10, nn = r & 1023;
            const int hh = colc >> 6, dd = colc & 63;
            ((unsigned short*)out)[(((size_t)(bb * H_ + hh) << 10) + nn) * 64 +
                                   dd] = f2bf(v);
          }
        }
      }
    }
  }
}

__global__ __launch_bounds__(256) void proj3(
    const float* __restrict__ q, const float* __restrict__ k,
    const float* __restrict__ v, const float* __restrict__ Wq,
    const float* __restrict__ Wk, const float* __restrict__ Wv,
    const float* __restrict__ bq, const float* __restrict__ bk,
    const float* __restrict__ bv, unsigned short* Qb, unsigned short* Kb,
    unsigned short* Vt) {
  const int wg = blockIdx.x;
  const int nid = (wg & 7) * 144 + (wg >> 3);
  const int x = nid % 6, y = (nid / 6) & 63, z = nid / 384;
  if (z == 0) gemm_body<1>(q, Wq, bq, Qb, y << 7, x << 7);
  else if (z == 1) gemm_body<1>(k, Wk, bk, Kb, y << 7, x << 7);
  else gemm_body<2>(v, Wv, bv, Vt, y << 7, x << 7);
}

__global__ __launch_bounds__(256) void oproj(
    const float* __restrict__ X, const float* __restrict__ Wo,
    const float* __restrict__ bo, float* __restrict__ out) {
  const int wg = blockIdx.x;
  const int nid = (wg & 7) * 48 + (wg >> 3);
  const int x = nid % 6, y = nid / 6;
  gemm_body<0>(X, Wo, bo, out, y << 7, x << 7);
}

// ============ fused: QK^T/8 -> 3x3 conv -> online softmax -> mix -> PV =====
// One block per (b, group, 30-row q-tile). 19 kv-steps of 56 cols.
// V in (B,H,D,N) layout -> coalesced staging of V^T tiles.
__global__ __launch_bounds__(256, 2) void fused_attn(
    const unsigned short* __restrict__ Qb, const unsigned short* __restrict__ Kb,
    const unsigned short* __restrict__ Vt, const float* __restrict__ cw,
    const float* __restrict__ hm, float* __restrict__ pvout) {
  __shared__ __align__(16) unsigned short Qs[2][32][72];
  __shared__ __align__(16) unsigned short Ks[2][64][72];
  __shared__ __align__(16) unsigned short Vs[2][64][72];  // [h][d][c], c<->j0+c
  __shared__ __align__(16) float raw[2][32][68];
  __shared__ __align__(16) unsigned short Pt[2][32][72];
  __shared__ float msum[2][32], lsum[2][32], alf[2][32];

  const int wg = blockIdx.x;  // 1680 = 8 * 210
  const int nid = (wg & 7) * 210 + (wg >> 3);
  const int qt = nid % NQT;
  const int bg = nid / NQT;
  const int g = bg % G_, bb = bg / G_;
  const int i0 = qt * QBLK;

  const int tid = threadIdx.x;
  const int wid = tid >> 6, lane = tid & 63;
  const int lr = lane & 15, lk = (lane >> 4) << 3;
  const int qrow = (lane >> 4) << 2;

  const size_t HSTR = (size_t)N_ * 64;
  const unsigned short* Qz = Qb + (size_t)(bb * H_ + 2 * g) * HSTR;
  const unsigned short* Kz = Kb + (size_t)(bb * H_ + 2 * g) * HSTR;
  const unsigned short* Vz = Vt + (size_t)(bb * H_ + 2 * g) * HSTR;  // [h][d][n]

  if (tid < 64) {
    const int h = tid >> 5, r = tid & 31;
    msum[h][r] = -3.0e38f; lsum[h][r] = 0.f; alf[h][r] = 1.f;
  }

  // staging roles
  const int krow = tid >> 2, kd0 = (tid & 3) << 4;  // K: row j0-1+krow, d chunk
  const int vd = tid >> 2, vc0 = (tid & 3) << 4;    // V: d row, col chunk

  u16x8 kreg[4], vreg[4];
  // prefetch step 0
  {
    const int j0 = 0;
    const int gj = j0 - 1 + krow;
#pragma unroll
    for (int h = 0; h < 2; ++h) {
      u16x8 a = {}, b = {};
      if (gj >= 0 && gj < N_) {
        a = *(const u16x8*)(Kz + h * HSTR + (size_t)gj * 64 + kd0);
        b = *(const u16x8*)(Kz + h * HSTR + (size_t)gj * 64 + kd0 + 8);
      }
      kreg[2 * h] = a; kreg[2 * h + 1] = b;
    }
#pragma unroll
    for (int h = 0; h < 2; ++h) {
#pragma unroll
      for (int hf = 0; hf < 2; ++hf) {
        const int c = vc0 + (hf << 3);
        u16x8 a = {};
        if (j0 + c < N_)
          a = *(const u16x8*)(Vz + h * HSTR + (size_t)vd * 1024 + j0 + c);
        vreg[2 * h + hf] = a;
      }
    }
  }

  // stage Q once (scaled by 1/8; OOB rows -> 0)
  {
    const int r = tid >> 3, d0 = (tid & 7) << 3;
    const int gi = i0 - 1 + r;
#pragma unroll
    for (int h = 0; h < 2; ++h) {
      u16x8 qv = {};
      if (gi >= 0 && gi < N_)
        qv = *(const u16x8*)(Qz + h * HSTR + (size_t)gi * 64 + d0);
#pragma unroll
      for (int e = 0; e < 8; ++e) qv[e] = f2bf(bf2f(qv[e]) * 0.125f);
      *(u16x8*)&Qs[h][r][d0] = qv;
    }
  }

  // conv role: head ch, row cri, col-quarter cc4
  const int ch = tid >> 7;
  const int cri = (tid >> 2) & 31;
  const int cc4 = tid & 3;
  const int cbase = cc4 << 4;
  float w9[9];
#pragma unroll
  for (int q = 0; q < 9; ++q) w9[q] = cw[(2 * g + ch) * 9 + q];

  const int qkh = wid >> 1, qkmt = wid & 1;
  const int pvh = wid >> 1, pvk = wid & 1;
  f32x4 acc[2][4] = {};

  for (int s = 0; s < NKS; ++s) {
    const int j0 = s * KSTEP;
    // ---- write staged K/V regs to LDS ----
    *(u16x8*)&Ks[0][krow][kd0] = kreg[0];
    *(u16x8*)&Ks[0][krow][kd0 + 8] = kreg[1];
    *(u16x8*)&Ks[1][krow][kd0] = kreg[2];
    *(u16x8*)&Ks[1][krow][kd0 + 8] = kreg[3];
    *(u16x8*)&Vs[0][vd][vc0] = vreg[0];
    *(u16x8*)&Vs[0][vd][vc0 + 8] = vreg[1];
    *(u16x8*)&Vs[1][vd][vc0] = vreg[2];
    *(u16x8*)&Vs[1][vd][vc0 + 8] = vreg[3];
    __syncthreads();  // B1

    // ---- issue global loads for step s+1 (latency hidden under compute) ----
    if (s + 1 < NKS) {
      const int j1 = j0 + KSTEP;
      const int gj = j1 - 1 + krow;
#pragma unroll
      for (int h = 0; h < 2; ++h) {
        u16x8 a = {}, b = {};
        if (gj >= 0 && gj < N_) {
          a = *(const u16x8*)(Kz + h * HSTR + (size_t)gj * 64 + kd0);
          b = *(const u16x8*)(Kz + h * HSTR + (size_t)gj * 64 + kd0 + 8);
        }
        kreg[2 * h] = a; kreg[2 * h + 1] = b;
      }
#pragma unroll
      for (int h = 0; h < 2; ++h) {
#pragma unroll
        for (int hf = 0; hf < 2; ++hf) {
          const int c = vc0 + (hf << 3);
          u16x8 a = {};
          if (j1 + c < N_)
            a = *(const u16x8*)(Vz + h * HSTR + (size_t)vd * 1024 + j1 + c);
          vreg[2 * h + hf] = a;
        }
      }
    }

    // ---- QK^T -> raw ----
    {
      f32x4 racc[4] = {};
#pragma unroll
      for (int d0 = 0; d0 < 64; d0 += 32) {
        const bf16x8 af = *(const bf16x8*)&Qs[qkh][(qkmt << 4) + lr][d0 + lk];
#pragma unroll
        for (int nt = 0; nt < 4; ++nt) {
          const bf16x8 bg = *(const bf16x8*)&Ks[qkh][(nt << 4) + lr][d0 + lk];
          racc[nt] =
              __builtin_amdgcn_mfma_f32_16x16x32_bf16(af, bg, racc[nt], 0, 0, 0);
        }
      }
#pragma unroll
      for (int nt = 0; nt < 4; ++nt)
#pragma unroll
        for (int q = 0; q < 4; ++q)
          raw[qkh][(qkmt << 4) + qrow + q][(nt << 4) + lr] = racc[nt][q];
    }
    __syncthreads();  // B2

    // ---- 3x3 conv + online softmax ----
    float P[16];
#pragma unroll
    for (int c = 0; c < 16; ++c) P[c] = 0.f;
    {
      const bool rvalid = (cri < QBLK) && (i0 + cri < N_);
      float pmax = -3.0e38f;
      if (rvalid) {
#pragma unroll
        for (int a2 = 0; a2 < 3; ++a2) {
          float rowv[20];
#pragma unroll
          for (int q4 = 0; q4 < 5; ++q4) {
            const float4 v = *(const float4*)&raw[ch][cri + a2][cbase + (q4 << 2)];
            rowv[q4 * 4 + 0] = v.x; rowv[q4 * 4 + 1] = v.y;
            rowv[q4 * 4 + 2] = v.z; rowv[q4 * 4 + 3] = v.w;
          }
          const float w0 = w9[a2 * 3], w1 = w9[a2 * 3 + 1], w2 = w9[a2 * 3 + 2];
#pragma unroll
          for (int c = 0; c < 16; ++c)
            P[c] = fmaf(rowv[c], w0,
                        fmaf(rowv[c + 1], w1, fmaf(rowv[c + 2], w2, P[c])));
        }
#pragma unroll
        for (int c = 0; c < 16; ++c)
          if ((cbase + c < KSTEP) && (j0 + cbase + c < N_)) pmax = fmaxf(pmax, P[c]);
      }
      pmax = fmaxf(pmax, __shfl_xor(pmax, 1));
      pmax = fmaxf(pmax, __shfl_xor(pmax, 2));
      if (rvalid) {
        const float m_old = msum[ch][cri];
        const float m_new = fmaxf(m_old, pmax);
        const float a = __expf(m_old - m_new);
        float rs = 0.f;
#pragma unroll
        for (int c = 0; c < 16; ++c) {
          const bool cv = (cbase + c < KSTEP) && (j0 + cbase + c < N_);
          const float pv = cv ? __expf(P[c] - m_new) : 0.f;
          P[c] = pv; rs += pv;
        }
        rs += __shfl_xor(rs, 1);
        rs += __shfl_xor(rs, 2);
        if (cc4 == 0) {
          msum[ch][cri] = m_new;
          lsum[ch][cri] = lsum[ch][cri] * a + rs;
          alf[ch][cri] = a;
        }
      } else {
#pragma unroll
        for (int c = 0; c < 16; ++c) P[c] = 0.f;
      }
    }
    // write P~ (bf16) into separate Pt buffer (no alias with raw)
    {
      u16x8 pa, pb;
#pragma unroll
      for (int e = 0; e < 8; ++e) { pa[e] = f2bf(P[e]); pb[e] = f2bf(P[8 + e]); }
      *(u16x8*)&Pt[ch][cri][cbase] = pa;
      *(u16x8*)&Pt[ch][cri][cbase + 8] = pb;
    }
    __syncthreads();  // B3

    // ---- PV: acc_{h,k} = acc*alpha + P~_h @ V_k ----
    {
#pragma unroll
      for (int mt = 0; mt < 2; ++mt)
#pragma unroll
        for (int q = 0; q < 4; ++q) {
          const float a = alf[pvh][(mt << 4) + qrow + q];
#pragma unroll
          for (int nt = 0; nt < 4; ++nt) acc[mt][nt][q] *= a;
        }
#pragma unroll
      for (int kj = 0; kj < 64; kj += 32) {
        bf16x8 af[2];
#pragma unroll
        for (int mt = 0; mt < 2; ++mt)
          af[mt] = *(const bf16x8*)&Pt[pvh][(mt << 4) + lr][kj + lk];
#pragma unroll
        for (int nt = 0; nt < 4; ++nt) {
          const bf16x8 bv = *(const bf16x8*)&Vs[pvk][(nt << 4) + lr][kj + lk];
#pragma unroll
          for (int mt = 0; mt < 2; ++mt)
            acc[mt][nt] = __builtin_amdgcn_mfma_f32_16x16x32_bf16(
                af[mt], bv, acc[mt][nt], 0, 0, 0);
        }
      }
    }
    __syncthreads();  // B4 (protects Ks/Vs/raw/Pt for next iteration)
  }

  // epilogue: O_k = hm[0,k]/l_0 * A_0k + hm[1,k]/l_1 * A_1k
  const float mixw = hm[(g * 2 + pvh) * 2 + pvk];
  float* Os = (float*)&Ks[0][0][0];  // [2][32][68]
  if (wid >= 2) {
#pragma unroll
    for (int mt = 0; mt < 2; ++mt)
#pragma unroll
      for (int q = 0; q < 4; ++q) {
        const int row = (mt << 4) + qrow + q;
        const float f = mixw / lsum[1][row];
#pragma unroll
        for (int nt = 0; nt < 4; ++nt)
          Os[(size_t)(pvk * 32 + row) * 68 + (nt << 4) + lr] = acc[mt][nt][q] * f;
      }
  }
  __syncthreads();
  if (wid < 2) {
#pragma unroll
    for (int mt = 0; mt < 2; ++mt)
#pragma unroll
      for (int q = 0; q < 4; ++q) {
        const int row = (mt << 4) + qrow + q;
        const int gi = i0 + row;
        if (row < QBLK && gi < N_) {
          const float f = mixw / lsum[0][row];
#pragma unroll
          for (int nt = 0; nt < 4; ++nt) {
            const float v = acc[mt][nt][q] * f +
                            Os[(size_t)(pvk * 32 + row) * 68 + (nt << 4) + lr];
            pvout[(size_t)(bb * N_ + gi) * C_ + (2 * g + pvk) * 64 + (nt << 4) +
                  lr] = v;
          }
        }
      }
  }
}

extern "C" void kernel_launch(void* const* d_in, const int* in_sizes, int n_in,
                              void* d_out, int out_size, void* d_ws, size_t ws_size,
                              hipStream_t stream) {
  const float* query = (const float*)d_in[0];
  const float* key   = (const float*)d_in[1];
  const float* value = (const float*)d_in[2];
  const float* Wq = (const float*)d_in[3];
  const float* bq = (const float*)d_in[4];
  const float* Wk = (const float*)d_in[5];
  const float* bk = (const float*)d_in[6];
  const float* Wv = (const float*)d_in[7];
  const float* bv = (const float*)d_in[8];
  const float* cw = (const float*)d_in[9];
  const float* hm = (const float*)d_in[10];
  const float* Wo = (const float*)d_in[11];
  const float* bo = (const float*)d_in[12];
  float* out = (float*)d_out;

  char* ws = (char*)d_ws;
  const size_t SZ_BF = (size_t)B_ * H_ * N_ * 64 * 2;  // 12,582,912 B
  unsigned short* Qb = (unsigned short*)ws;
  unsigned short* Kb = (unsigned short*)(ws + SZ_BF);
  unsigned short* Vt = (unsigned short*)(ws + 2 * SZ_BF);  // (B,H,D,N)
  float* pvout = (float*)(ws + 3 * SZ_BF);                 // 25,165,824 B

  const dim3 blk(256);
  proj3<<<dim3(1152), blk, 0, stream>>>(query, key, value, Wq, Wk, Wv, bq, bk, bv,
                                        Qb, Kb, Vt);
  fused_attn<<<dim3(1680), blk, 0, stream>>>(Qb, Kb, Vt, cw, hm, pvout);
  oproj<<<dim3(384), blk, 0, stream>>>(pvout, Wo, bo, out);
}

// Round 6
// 255.675 us; speedup vs baseline: 5.8607x; 1.3344x over previous
//
#include <hip/hip_runtime.h>
#include <stdint.h>

#define B_ 8
#define N_ 1024
#define C_ 768
#define H_ 12
#define G_ 6
#define QBLK 32
#define KSTEP 64
#define NQT 32   // 1024/32
#define NKS 16   // 1024/64

typedef __attribute__((ext_vector_type(8))) short bf16x8;
typedef __attribute__((ext_vector_type(8))) unsigned short u16x8;
typedef __attribute__((ext_vector_type(4))) float f32x4;

__device__ __forceinline__ float bf2f(unsigned short u) {
  return __uint_as_float(((unsigned)u) << 16);
}
__device__ __forceinline__ unsigned short f2bf(float f) {
  unsigned x = __float_as_uint(f);
  unsigned r = x + 0x7fffu + ((x >> 16) & 1u);  // RNE
  return (unsigned short)(r >> 16);
}

// ================= MFMA GEMM body: out = X @ W^T + bias ====================
// 128x128 tile, BK=32, 4 waves.
// MODE 0: fp32 out [M][768]. MODE 1: bf16 (B,H,N,D). MODE 2: bf16 (B,H,D,N).
template <int MODE>
__device__ __forceinline__ void gemm_body(
    const float* __restrict__ X, const float* __restrict__ W,
    const float* __restrict__ bias, void* __restrict__ out,
    int row0, int col0) {
  __shared__ __align__(16) unsigned short As[128][40];
  __shared__ __align__(16) unsigned short Bs[128][40];
  const int tid = threadIdx.x;
  const int wid = tid >> 6, lane = tid & 63;
  const int lr = lane & 15, lk = (lane >> 4) << 3;
  const int qrow = (lane >> 4) << 2;
  const int wr = (wid & 1) << 6, wc = (wid >> 1) << 6;
  const int srow = tid >> 3, scol = (tid & 7) << 2;
  f32x4 acc[4][4] = {};
  for (int k0 = 0; k0 < C_; k0 += 32) {
#pragma unroll
    for (int it = 0; it < 4; ++it) {
      const int r = srow + (it << 5);
      const float4 va = *(const float4*)(X + (size_t)(row0 + r) * C_ + k0 + scol);
      const float4 vb = *(const float4*)(W + (size_t)(col0 + r) * C_ + k0 + scol);
      *(ushort4*)&As[r][scol] =
          make_ushort4(f2bf(va.x), f2bf(va.y), f2bf(va.z), f2bf(va.w));
      *(ushort4*)&Bs[r][scol] =
          make_ushort4(f2bf(vb.x), f2bf(vb.y), f2bf(vb.z), f2bf(vb.w));
    }
    __syncthreads();
    bf16x8 af[4], bg[4];
#pragma unroll
    for (int m = 0; m < 4; ++m) af[m] = *(const bf16x8*)&As[wr + (m << 4) + lr][lk];
#pragma unroll
    for (int n = 0; n < 4; ++n) bg[n] = *(const bf16x8*)&Bs[wc + (n << 4) + lr][lk];
#pragma unroll
    for (int m = 0; m < 4; ++m)
#pragma unroll
      for (int n = 0; n < 4; ++n)
        acc[m][n] = __builtin_amdgcn_mfma_f32_16x16x32_bf16(af[m], bg[n],
                                                            acc[m][n], 0, 0, 0);
    __syncthreads();
  }
#pragma unroll
  for (int m = 0; m < 4; ++m) {
#pragma unroll
    for (int n = 0; n < 4; ++n) {
      const int colc = col0 + wc + (n << 4) + lr;
      const float bv = bias[colc];
      if (MODE == 2) {
        const int r0 = row0 + wr + (m << 4) + qrow;
        const int bb = r0 >> 10, nn0 = r0 & 1023;
        const int hh = colc >> 6, dd = colc & 63;
        ushort4 pk;
        pk.x = f2bf(acc[m][n][0] + bv);
        pk.y = f2bf(acc[m][n][1] + bv);
        pk.z = f2bf(acc[m][n][2] + bv);
        pk.w = f2bf(acc[m][n][3] + bv);
        *(ushort4*)&((unsigned short*)out)[(((size_t)(bb * H_ + hh) << 6) + dd)
                                               * 1024 + nn0] = pk;
      } else {
#pragma unroll
        for (int q = 0; q < 4; ++q) {
          const int r = row0 + wr + (m << 4) + qrow + q;
          const float v = acc[m][n][q] + bv;
          if (MODE == 0) {
            ((float*)out)[(size_t)r * C_ + colc] = v;
          } else {
            const int bb = r >> 10, nn = r & 1023;
            const int hh = colc >> 6, dd = colc & 63;
            ((unsigned short*)out)[(((size_t)(bb * H_ + hh) << 10) + nn) * 64 +
                                   dd] = f2bf(v);
          }
        }
      }
    }
  }
}

__global__ __launch_bounds__(256) void proj3(
    const float* __restrict__ q, const float* __restrict__ k,
    const float* __restrict__ v, const float* __restrict__ Wq,
    const float* __restrict__ Wk, const float* __restrict__ Wv,
    const float* __restrict__ bq, const float* __restrict__ bk,
    const float* __restrict__ bv, unsigned short* Qb, unsigned short* Kb,
    unsigned short* Vt) {
  const int wg = blockIdx.x;
  const int nid = (wg & 7) * 144 + (wg >> 3);
  const int x = nid % 6, y = (nid / 6) & 63, z = nid / 384;
  if (z == 0) gemm_body<1>(q, Wq, bq, Qb, y << 7, x << 7);
  else if (z == 1) gemm_body<1>(k, Wk, bk, Kb, y << 7, x << 7);
  else gemm_body<2>(v, Wv, bv, Vt, y << 7, x << 7);
}

__global__ __launch_bounds__(256) void oproj(
    const float* __restrict__ X, const float* __restrict__ Wo,
    const float* __restrict__ bo, float* __restrict__ out) {
  const int wg = blockIdx.x;
  const int nid = (wg & 7) * 48 + (wg >> 3);
  const int x = nid % 6, y = nid / 6;
  gemm_body<0>(X, Wo, bo, out, y << 7, x << 7);
}

// ============ fused: conv-folded QK^T -> online softmax -> mix -> PV =======
// conv[i,j] = sum_c Qt_c[i] . K[j+c-1],  Qt_c[i] = sum_a (w[a,c]/8) Q[i+a-1]
// One block per (b, group, 32-row q-tile). 16 kv-steps of 64 cols (no masks).
__global__ __launch_bounds__(256, 3) void fused_attn(
    const unsigned short* __restrict__ Qb, const unsigned short* __restrict__ Kb,
    const unsigned short* __restrict__ Vt, const float* __restrict__ cw,
    const float* __restrict__ hm, float* __restrict__ pvout) {
  __shared__ __align__(16) unsigned short Ks[2][66][72];   // row r <-> j0-1+r
  __shared__ __align__(16) unsigned short Vs[2][64][72];   // [h][d][c]
  __shared__ __align__(16) unsigned short QsPt[2][34][72]; // Q stage, then Pt
  __shared__ float alf[2][32], lsum[2][32];

  const int wg = blockIdx.x;  // 1536 = 8 * 192
  const int nid = (wg & 7) * 192 + (wg >> 3);
  const int qt = nid & 31;
  const int bg = nid >> 5;
  const int g = bg % G_, bb = bg / G_;
  const int i0 = qt << 5;

  const int tid = threadIdx.x;
  const int wid = tid >> 6, lane = tid & 63;
  const int lr = lane & 15, lk = (lane >> 4) << 3;
  const int qrow = (lane >> 4) << 2;

  const size_t HSTR = (size_t)N_ * 64;
  const unsigned short* Qz = Qb + (size_t)(bb * H_ + 2 * g) * HSTR;
  const unsigned short* Kz = Kb + (size_t)(bb * H_ + 2 * g) * HSTR;
  const unsigned short* Vz = Vt + (size_t)(bb * H_ + 2 * g) * HSTR;  // [h][d][n]

  // staging roles
  const int krow = tid >> 2, kd0 = (tid & 3) << 4;   // K main rows 0..63
  const int k2r = 64 + (tid >> 3), k2d = (tid & 7) << 3;  // halo rows 64,65 (tid<16)
  const int vd = tid >> 2, vc0 = (tid & 3) << 4;     // V^T rows

  u16x8 kreg[4], vreg[4];
  u16x8 kreg2[2];

  // ---- prefetch step 0 ----
  {
    const int gj = -1 + krow;
#pragma unroll
    for (int h = 0; h < 2; ++h) {
      u16x8 a = {}, b = {};
      if (gj >= 0) {
        a = *(const u16x8*)(Kz + h * HSTR + (size_t)gj * 64 + kd0);
        b = *(const u16x8*)(Kz + h * HSTR + (size_t)gj * 64 + kd0 + 8);
      }
      kreg[2 * h] = a; kreg[2 * h + 1] = b;
    }
    if (tid < 16) {
      const int gj2 = -1 + k2r;  // 63 or 64
#pragma unroll
      for (int h = 0; h < 2; ++h)
        kreg2[h] = *(const u16x8*)(Kz + h * HSTR + (size_t)gj2 * 64 + k2d);
    }
#pragma unroll
    for (int h = 0; h < 2; ++h)
#pragma unroll
      for (int hf = 0; hf < 2; ++hf)
        vreg[2 * h + hf] =
            *(const u16x8*)(Vz + h * HSTR + (size_t)vd * 1024 + vc0 + (hf << 3));
  }

  // ---- stage Q rows i0-1 .. i0+32 (34 rows, OOB -> 0) ----
  {
    const int r = tid >> 3, d0 = (tid & 7) << 3;
    {
      const int gi = i0 - 1 + r;
#pragma unroll
      for (int h = 0; h < 2; ++h) {
        u16x8 qv = {};
        if (gi >= 0 && gi < N_)
          qv = *(const u16x8*)(Qz + h * HSTR + (size_t)gi * 64 + d0);
        *(u16x8*)&QsPt[h][r][d0] = qv;
      }
    }
    if (tid < 16) {
      const int r2 = 32 + (tid >> 3);
      const int gi = i0 - 1 + r2;
#pragma unroll
      for (int h = 0; h < 2; ++h) {
        u16x8 qv = {};
        if (gi < N_) qv = *(const u16x8*)(Qz + h * HSTR + (size_t)gi * 64 + d0);
        *(u16x8*)&QsPt[h][r2][d0] = qv;
      }
    }
  }
  __syncthreads();  // Q staged

  // ---- extract Qtilde A-fragments (held in regs for whole kernel) ----
  const int qkh = wid >> 1, qkmt = wid & 1;
  const int pvh = qkh, pvk = qkmt;
  bf16x8 qtf[3][2];  // [c][d0-half]
  {
    float wc3[3][3];
#pragma unroll
    for (int a = 0; a < 3; ++a)
#pragma unroll
      for (int c = 0; c < 3; ++c)
        wc3[a][c] = cw[(2 * g + qkh) * 9 + a * 3 + c] * 0.125f;
    const int ribase = (qkmt << 4) + lr;
#pragma unroll
    for (int dh = 0; dh < 2; ++dh) {
      const u16x8 qa = *(const u16x8*)&QsPt[qkh][ribase + 0][(dh << 5) + lk];
      const u16x8 qb = *(const u16x8*)&QsPt[qkh][ribase + 1][(dh << 5) + lk];
      const u16x8 qc = *(const u16x8*)&QsPt[qkh][ribase + 2][(dh << 5) + lk];
#pragma unroll
      for (int c = 0; c < 3; ++c) {
#pragma unroll
        for (int e = 0; e < 8; ++e) {
          const float v = bf2f(qa[e]) * wc3[0][c] + bf2f(qb[e]) * wc3[1][c] +
                          bf2f(qc[e]) * wc3[2][c];
          qtf[c][dh][e] = (short)f2bf(v);
        }
      }
    }
  }

  float mreg[4] = {-3.0e38f, -3.0e38f, -3.0e38f, -3.0e38f};
  float lreg[4] = {0.f, 0.f, 0.f, 0.f};
  f32x4 acc[2][4] = {};

  for (int s = 0; s < NKS; ++s) {
    // ---- phase 1: write staged K/V regs to LDS ----
    *(u16x8*)&Ks[0][krow][kd0] = kreg[0];
    *(u16x8*)&Ks[0][krow][kd0 + 8] = kreg[1];
    *(u16x8*)&Ks[1][krow][kd0] = kreg[2];
    *(u16x8*)&Ks[1][krow][kd0 + 8] = kreg[3];
    if (tid < 16) {
      *(u16x8*)&Ks[0][k2r][k2d] = kreg2[0];
      *(u16x8*)&Ks[1][k2r][k2d] = kreg2[1];
    }
    *(u16x8*)&Vs[0][vd][vc0] = vreg[0];
    *(u16x8*)&Vs[0][vd][vc0 + 8] = vreg[1];
    *(u16x8*)&Vs[1][vd][vc0] = vreg[2];
    *(u16x8*)&Vs[1][vd][vc0 + 8] = vreg[3];
    __syncthreads();  // B1

    // ---- phase 2: issue loads for step s+1 ----
    if (s + 1 < NKS) {
      const int j1 = (s + 1) << 6;
      const int gj = j1 - 1 + krow;  // >= 63, <= 1022: always valid
#pragma unroll
      for (int h = 0; h < 2; ++h) {
        kreg[2 * h] = *(const u16x8*)(Kz + h * HSTR + (size_t)gj * 64 + kd0);
        kreg[2 * h + 1] =
            *(const u16x8*)(Kz + h * HSTR + (size_t)gj * 64 + kd0 + 8);
      }
      if (tid < 16) {
        const int gj2 = j1 - 1 + k2r;  // j1+63 or j1+64
#pragma unroll
        for (int h = 0; h < 2; ++h) {
          u16x8 a = {};
          if (gj2 < N_)
            a = *(const u16x8*)(Kz + h * HSTR + (size_t)gj2 * 64 + k2d);
          kreg2[h] = a;
        }
      }
#pragma unroll
      for (int h = 0; h < 2; ++h)
#pragma unroll
        for (int hf = 0; hf < 2; ++hf)
          vreg[2 * h + hf] = *(const u16x8*)(Vz + h * HSTR + (size_t)vd * 1024 +
                                             j1 + vc0 + (hf << 3));
    }

    // ---- phase 3: conv-folded QK^T (K-dim 192 via 3 shifted K views) ----
    f32x4 racc[4] = {};
#pragma unroll
    for (int c = 0; c < 3; ++c) {
#pragma unroll
      for (int dh = 0; dh < 2; ++dh) {
        const bf16x8 af = qtf[c][dh];
#pragma unroll
        for (int nt = 0; nt < 4; ++nt) {
          const bf16x8 bg =
              *(const bf16x8*)&Ks[qkh][(nt << 4) + lr + c][(dh << 5) + lk];
          racc[nt] =
              __builtin_amdgcn_mfma_f32_16x16x32_bf16(af, bg, racc[nt], 0, 0, 0);
        }
      }
    }

    // ---- phase 4: online softmax in registers ----
    {
      float mloc[4], alpha4[4], rs[4];
#pragma unroll
      for (int q = 0; q < 4; ++q)
        mloc[q] = fmaxf(fmaxf(racc[0][q], racc[1][q]),
                        fmaxf(racc[2][q], racc[3][q]));
#pragma unroll
      for (int off = 1; off <= 8; off <<= 1)
#pragma unroll
        for (int q = 0; q < 4; ++q)
          mloc[q] = fmaxf(mloc[q], __shfl_xor(mloc[q], off));
#pragma unroll
      for (int q = 0; q < 4; ++q) {
        const float mn = fmaxf(mreg[q], mloc[q]);
        alpha4[q] = __expf(mreg[q] - mn);
        mreg[q] = mn;
        float r = 0.f;
#pragma unroll
        for (int nt = 0; nt < 4; ++nt) {
          const float p = __expf(racc[nt][q] - mn);
          racc[nt][q] = p;
          r += p;
        }
        rs[q] = r;
      }
#pragma unroll
      for (int off = 1; off <= 8; off <<= 1)
#pragma unroll
        for (int q = 0; q < 4; ++q) rs[q] += __shfl_xor(rs[q], off);
#pragma unroll
      for (int q = 0; q < 4; ++q) lreg[q] = lreg[q] * alpha4[q] + rs[q];
      // write P~ (bf16) into Pt (aliases Q stage, rows 0..31)
#pragma unroll
      for (int nt = 0; nt < 4; ++nt)
#pragma unroll
        for (int q = 0; q < 4; ++q)
          QsPt[qkh][(qkmt << 4) + qrow + q][(nt << 4) + lr] = f2bf(racc[nt][q]);
      if (lr == 0) {
#pragma unroll
        for (int q = 0; q < 4; ++q)
          alf[qkh][(qkmt << 4) + qrow + q] = alpha4[q];
      }
    }
    __syncthreads();  // B2

    // ---- phase 5: PV: acc = acc*alpha + P~ @ V ----
    {
#pragma unroll
      for (int mt = 0; mt < 2; ++mt)
#pragma unroll
        for (int q = 0; q < 4; ++q) {
          const float a = alf[pvh][(mt << 4) + qrow + q];
#pragma unroll
          for (int nt = 0; nt < 4; ++nt) acc[mt][nt][q] *= a;
        }
#pragma unroll
      for (int kj = 0; kj < 64; kj += 32) {
        bf16x8 af[2];
#pragma unroll
        for (int mt = 0; mt < 2; ++mt)
          af[mt] = *(const bf16x8*)&QsPt[pvh][(mt << 4) + lr][kj + lk];
#pragma unroll
        for (int nt = 0; nt < 4; ++nt) {
          const bf16x8 bv = *(const bf16x8*)&Vs[pvk][(nt << 4) + lr][kj + lk];
#pragma unroll
          for (int mt = 0; mt < 2; ++mt)
            acc[mt][nt] = __builtin_amdgcn_mfma_f32_16x16x32_bf16(
                af[mt], bv, acc[mt][nt], 0, 0, 0);
        }
      }
    }
    __syncthreads();  // B3
  }

  // ---- epilogue: O_k = sum_h hm[h,k]/l_h * A_hk ----
  if (lr == 0) {
#pragma unroll
    for (int q = 0; q < 4; ++q)
      lsum[qkh][(qkmt << 4) + qrow + q] = lreg[q];
  }
  __syncthreads();

  const float mixw = hm[(g * 2 + pvh) * 2 + pvk];
  float* Os = (float*)&Ks[0][0][0];  // [2][32][68]
  if (wid >= 2) {
#pragma unroll
    for (int mt = 0; mt < 2; ++mt)
#pragma unroll
      for (int q = 0; q < 4; ++q) {
        const int row = (mt << 4) + qrow + q;
        const float f = mixw / lsum[1][row];
#pragma unroll
        for (int nt = 0; nt < 4; ++nt)
          Os[(size_t)(pvk * 32 + row) * 68 + (nt << 4) + lr] = acc[mt][nt][q] * f;
      }
  }
  __syncthreads();
  if (wid < 2) {
#pragma unroll
    for (int mt = 0; mt < 2; ++mt)
#pragma unroll
      for (int q = 0; q < 4; ++q) {
        const int row = (mt << 4) + qrow + q;
        const int gi = i0 + row;
        const float f = mixw / lsum[0][row];
#pragma unroll
        for (int nt = 0; nt < 4; ++nt) {
          const float v = acc[mt][nt][q] * f +
                          Os[(size_t)(pvk * 32 + row) * 68 + (nt << 4) + lr];
          pvout[(size_t)(bb * N_ + gi) * C_ + (2 * g + pvk) * 64 + (nt << 4) +
                lr] = v;
        }
      }
  }
}

extern "C" void kernel_launch(void* const* d_in, const int* in_sizes, int n_in,
                              void* d_out, int out_size, void* d_ws, size_t ws_size,
                              hipStream_t stream) {
  const float* query = (const float*)d_in[0];
  const float* key   = (const float*)d_in[1];
  const float* value = (const float*)d_in[2];
  const float* Wq = (const float*)d_in[3];
  const float* bq = (const float*)d_in[4];
  const float* Wk = (const float*)d_in[5];
  const float* bk = (const float*)d_in[6];
  const float* Wv = (const float*)d_in[7];
  const float* bv = (const float*)d_in[8];
  const float* cw = (const float*)d_in[9];
  const float* hm = (const float*)d_in[10];
  const float* Wo = (const float*)d_in[11];
  const float* bo = (const float*)d_in[12];
  float* out = (float*)d_out;

  char* ws = (char*)d_ws;
  const size_t SZ_BF = (size_t)B_ * H_ * N_ * 64 * 2;  // 12,582,912 B
  unsigned short* Qb = (unsigned short*)ws;
  unsigned short* Kb = (unsigned short*)(ws + SZ_BF);
  unsigned short* Vt = (unsigned short*)(ws + 2 * SZ_BF);  // (B,H,D,N)
  float* pvout = (float*)(ws + 3 * SZ_BF);                 // 25,165,824 B

  const dim3 blk(256);
  proj3<<<dim3(1152), blk, 0, stream>>>(query, key, value, Wq, Wk, Wv, bq, bk, bv,
                                        Qb, Kb, Vt);
  fused_attn<<<dim3(1536), blk, 0, stream>>>(Qb, Kb, Vt, cw, hm, pvout);
  oproj<<<dim3(384), blk, 0, stream>>>(pvout, Wo, bo, out);
}

// Round 7
// 232.404 us; speedup vs baseline: 6.4476x; 1.1001x over previous
//
#include <hip/hip_runtime.h>
#include <stdint.h>

#define B_ 8
#define N_ 1024
#define C_ 768
#define H_ 12
#define G_ 6
#define QBLK 32
#define KSTEP 64
#define NQT 32   // 1024/32
#define NKS 16   // 1024/64

typedef __attribute__((ext_vector_type(8))) short bf16x8;
typedef __attribute__((ext_vector_type(8))) unsigned short u16x8;
typedef __attribute__((ext_vector_type(4))) float f32x4;

__device__ __forceinline__ float bf2f(unsigned short u) {
  return __uint_as_float(((unsigned)u) << 16);
}
__device__ __forceinline__ unsigned short f2bf(float f) {
  unsigned x = __float_as_uint(f);
  unsigned r = x + 0x7fffu + ((x >> 16) & 1u);  // RNE
  return (unsigned short)(r >> 16);
}

// ================= MFMA GEMM body: out = X @ W^T + bias ====================
// 128x128 tile, BK=32, 4 waves.
// MODE 0: fp32 out [M][768]. MODE 1: bf16 (B,H,N,D). MODE 2: bf16 (B,H,D,N).
template <int MODE>
__device__ __forceinline__ void gemm_body(
    const float* __restrict__ X, const float* __restrict__ W,
    const float* __restrict__ bias, void* __restrict__ out,
    int row0, int col0) {
  __shared__ __align__(16) unsigned short As[128][40];
  __shared__ __align__(16) unsigned short Bs[128][40];
  const int tid = threadIdx.x;
  const int wid = tid >> 6, lane = tid & 63;
  const int lr = lane & 15, lk = (lane >> 4) << 3;
  const int qrow = (lane >> 4) << 2;
  const int wr = (wid & 1) << 6, wc = (wid >> 1) << 6;
  const int srow = tid >> 3, scol = (tid & 7) << 2;
  f32x4 acc[4][4] = {};
  for (int k0 = 0; k0 < C_; k0 += 32) {
#pragma unroll
    for (int it = 0; it < 4; ++it) {
      const int r = srow + (it << 5);
      const float4 va = *(const float4*)(X + (size_t)(row0 + r) * C_ + k0 + scol);
      const float4 vb = *(const float4*)(W + (size_t)(col0 + r) * C_ + k0 + scol);
      *(ushort4*)&As[r][scol] =
          make_ushort4(f2bf(va.x), f2bf(va.y), f2bf(va.z), f2bf(va.w));
      *(ushort4*)&Bs[r][scol] =
          make_ushort4(f2bf(vb.x), f2bf(vb.y), f2bf(vb.z), f2bf(vb.w));
    }
    __syncthreads();
    bf16x8 af[4], bg[4];
#pragma unroll
    for (int m = 0; m < 4; ++m) af[m] = *(const bf16x8*)&As[wr + (m << 4) + lr][lk];
#pragma unroll
    for (int n = 0; n < 4; ++n) bg[n] = *(const bf16x8*)&Bs[wc + (n << 4) + lr][lk];
#pragma unroll
    for (int m = 0; m < 4; ++m)
#pragma unroll
      for (int n = 0; n < 4; ++n)
        acc[m][n] = __builtin_amdgcn_mfma_f32_16x16x32_bf16(af[m], bg[n],
                                                            acc[m][n], 0, 0, 0);
    __syncthreads();
  }
#pragma unroll
  for (int m = 0; m < 4; ++m) {
#pragma unroll
    for (int n = 0; n < 4; ++n) {
      const int colc = col0 + wc + (n << 4) + lr;
      const float bv = bias[colc];
      if (MODE == 2) {
        const int r0 = row0 + wr + (m << 4) + qrow;
        const int bb = r0 >> 10, nn0 = r0 & 1023;
        const int hh = colc >> 6, dd = colc & 63;
        ushort4 pk;
        pk.x = f2bf(acc[m][n][0] + bv);
        pk.y = f2bf(acc[m][n][1] + bv);
        pk.z = f2bf(acc[m][n][2] + bv);
        pk.w = f2bf(acc[m][n][3] + bv);
        *(ushort4*)&((unsigned short*)out)[(((size_t)(bb * H_ + hh) << 6) + dd)
                                               * 1024 + nn0] = pk;
      } else {
#pragma unroll
        for (int q = 0; q < 4; ++q) {
          const int r = row0 + wr + (m << 4) + qrow + q;
          const float v = acc[m][n][q] + bv;
          if (MODE == 0) {
            ((float*)out)[(size_t)r * C_ + colc] = v;
          } else {
            const int bb = r >> 10, nn = r & 1023;
            const int hh = colc >> 6, dd = colc & 63;
            ((unsigned short*)out)[(((size_t)(bb * H_ + hh) << 10) + nn) * 64 +
                                   dd] = f2bf(v);
          }
        }
      }
    }
  }
}

__global__ __launch_bounds__(256) void proj3(
    const float* __restrict__ q, const float* __restrict__ k,
    const float* __restrict__ v, const float* __restrict__ Wq,
    const float* __restrict__ Wk, const float* __restrict__ Wv,
    const float* __restrict__ bq, const float* __restrict__ bk,
    const float* __restrict__ bv, unsigned short* Qb, unsigned short* Kb,
    unsigned short* Vt) {
  const int wg = blockIdx.x;
  const int nid = (wg & 7) * 144 + (wg >> 3);
  const int x = nid % 6, y = (nid / 6) & 63, z = nid / 384;
  if (z == 0) gemm_body<1>(q, Wq, bq, Qb, y << 7, x << 7);
  else if (z == 1) gemm_body<1>(k, Wk, bk, Kb, y << 7, x << 7);
  else gemm_body<2>(v, Wv, bv, Vt, y << 7, x << 7);
}

__global__ __launch_bounds__(256) void oproj(
    const float* __restrict__ X, const float* __restrict__ Wo,
    const float* __restrict__ bo, float* __restrict__ out) {
  const int wg = blockIdx.x;
  const int nid = (wg & 7) * 48 + (wg >> 3);
  const int x = nid % 6, y = nid / 6;
  gemm_body<0>(X, Wo, bo, out, y << 7, x << 7);
}

// ============ fused: conv-folded QK^T (swapped) -> reg softmax -> PV =======
// Swapped mfma: racc = mfma(A=K_frag, B=Qt_frag) => lane owns ONE q-column
// (col = lane&15), 16 k-values (4 nt x 4 q). Softmax is per-lane + 2 shfl.
// P~ round-trip is wave-private (no barrier).
__global__ __launch_bounds__(256, 3) void fused_attn(
    const unsigned short* __restrict__ Qb, const unsigned short* __restrict__ Kb,
    const unsigned short* __restrict__ Vt, const float* __restrict__ cw,
    const float* __restrict__ hm, float* __restrict__ pvout) {
  __shared__ __align__(16) unsigned short Ks[2][66][72];   // row r <-> j0-1+r
  __shared__ __align__(16) unsigned short Vs[2][64][72];   // [h][d][c]
  __shared__ __align__(16) unsigned short QPt[4896];       // Q stage / per-wave Pt
  __shared__ float lsum[2][32];

  const int wg = blockIdx.x;  // 1536 = 8 * 192
  const int nid = (wg & 7) * 192 + (wg >> 3);
  const int qt = nid & 31;
  const int bg = nid >> 5;
  const int g = bg % G_, bb = bg / G_;
  const int i0 = qt << 5;

  const int tid = threadIdx.x;
  const int wid = tid >> 6, lane = tid & 63;
  const int lr = lane & 15, lg = lane >> 4;
  const int lk = lg << 3;

  const int h = wid >> 1, mt = wid & 1;  // wave role: (head, q-row tile)

  const size_t HSTR = (size_t)N_ * 64;
  const unsigned short* Qz = Qb + (size_t)(bb * H_ + 2 * g) * HSTR;
  const unsigned short* Kz = Kb + (size_t)(bb * H_ + 2 * g) * HSTR;
  const unsigned short* Vz = Vt + (size_t)(bb * H_ + 2 * g) * HSTR;  // [h][d][n]

  // staging roles
  const int krow = tid >> 2, kd0 = (tid & 3) << 4;        // K rows 0..63
  const int k2r = 64 + (tid >> 3), k2d = (tid & 7) << 3;  // halo rows (tid<16)
  const int vd = tid >> 2, vc0 = (tid & 3) << 4;          // V^T rows

  u16x8 kreg[4], vreg[4];
  u16x8 kreg2[2];

  // ---- prefetch step 0 ----
  {
    const int gj = -1 + krow;
#pragma unroll
    for (int hh = 0; hh < 2; ++hh) {
      u16x8 a = {}, b = {};
      if (gj >= 0) {
        a = *(const u16x8*)(Kz + hh * HSTR + (size_t)gj * 64 + kd0);
        b = *(const u16x8*)(Kz + hh * HSTR + (size_t)gj * 64 + kd0 + 8);
      }
      kreg[2 * hh] = a; kreg[2 * hh + 1] = b;
    }
    if (tid < 16) {
      const int gj2 = -1 + k2r;  // 63 or 64
#pragma unroll
      for (int hh = 0; hh < 2; ++hh)
        kreg2[hh] = *(const u16x8*)(Kz + hh * HSTR + (size_t)gj2 * 64 + k2d);
    }
#pragma unroll
    for (int hh = 0; hh < 2; ++hh)
#pragma unroll
      for (int hf = 0; hf < 2; ++hf)
        vreg[2 * hh + hf] =
            *(const u16x8*)(Vz + hh * HSTR + (size_t)vd * 1024 + vc0 + (hf << 3));
  }

  // ---- stage Q rows i0-1 .. i0+32 (34 rows, OOB -> 0) into QPt ----
  {
    const int r = tid >> 3, d0 = (tid & 7) << 3;
    {
      const int gi = i0 - 1 + r;
#pragma unroll
      for (int hh = 0; hh < 2; ++hh) {
        u16x8 qv = {};
        if (gi >= 0 && gi < N_)
          qv = *(const u16x8*)(Qz + hh * HSTR + (size_t)gi * 64 + d0);
        *(u16x8*)&QPt[((size_t)(hh * 34 + r)) * 72 + d0] = qv;
      }
    }
    if (tid < 16) {
      const int r2 = 32 + (tid >> 3);
      const int gi = i0 - 1 + r2;
#pragma unroll
      for (int hh = 0; hh < 2; ++hh) {
        u16x8 qv = {};
        if (gi < N_) qv = *(const u16x8*)(Qz + hh * HSTR + (size_t)gi * 64 + d0);
        *(u16x8*)&QPt[((size_t)(hh * 34 + r2)) * 72 + d0] = qv;
      }
    }
  }
  __syncthreads();  // Q staged

  // ---- extract Qtilde fragments (B-operand; rows (mt<<4)+lr) ----
  bf16x8 qtf[3][2];  // [c][dh]
  {
    float wc3[3][3];
#pragma unroll
    for (int a = 0; a < 3; ++a)
#pragma unroll
      for (int c = 0; c < 3; ++c)
        wc3[a][c] = cw[(2 * g + h) * 9 + a * 3 + c] * 0.125f;
    const int ribase = (mt << 4) + lr;
#pragma unroll
    for (int dh = 0; dh < 2; ++dh) {
      const u16x8 qa = *(const u16x8*)&QPt[((size_t)(h * 34 + ribase + 0)) * 72 +
                                           (dh << 5) + lk];
      const u16x8 qb = *(const u16x8*)&QPt[((size_t)(h * 34 + ribase + 1)) * 72 +
                                           (dh << 5) + lk];
      const u16x8 qc = *(const u16x8*)&QPt[((size_t)(h * 34 + ribase + 2)) * 72 +
                                           (dh << 5) + lk];
#pragma unroll
      for (int c = 0; c < 3; ++c) {
#pragma unroll
        for (int e = 0; e < 8; ++e) {
          const float v = bf2f(qa[e]) * wc3[0][c] + bf2f(qb[e]) * wc3[1][c] +
                          bf2f(qc[e]) * wc3[2][c];
          qtf[c][dh][e] = (short)f2bf(v);
        }
      }
    }
  }
  // (B1 of step 0 fences all waves' Q reads before first Pt overwrite.)

  unsigned short* PtW = &QPt[(size_t)wid * 16 * 72];  // wave-private [16][72]

  float mreg = -3.0e38f, lreg = 0.f;  // for q-column qr = mt*16+lr
  f32x4 acc[2][4] = {};               // [v-head k][nt(d)]

  for (int s = 0; s < NKS; ++s) {
    // ---- phase 1: write staged K/V regs to LDS ----
    *(u16x8*)&Ks[0][krow][kd0] = kreg[0];
    *(u16x8*)&Ks[0][krow][kd0 + 8] = kreg[1];
    *(u16x8*)&Ks[1][krow][kd0] = kreg[2];
    *(u16x8*)&Ks[1][krow][kd0 + 8] = kreg[3];
    if (tid < 16) {
      *(u16x8*)&Ks[0][k2r][k2d] = kreg2[0];
      *(u16x8*)&Ks[1][k2r][k2d] = kreg2[1];
    }
    *(u16x8*)&Vs[0][vd][vc0] = vreg[0];
    *(u16x8*)&Vs[0][vd][vc0 + 8] = vreg[1];
    *(u16x8*)&Vs[1][vd][vc0] = vreg[2];
    *(u16x8*)&Vs[1][vd][vc0 + 8] = vreg[3];
    __syncthreads();  // B1

    // ---- phase 2: issue loads for step s+1 ----
    if (s + 1 < NKS) {
      const int j1 = (s + 1) << 6;
      const int gj = j1 - 1 + krow;
#pragma unroll
      for (int hh = 0; hh < 2; ++hh) {
        kreg[2 * hh] = *(const u16x8*)(Kz + hh * HSTR + (size_t)gj * 64 + kd0);
        kreg[2 * hh + 1] =
            *(const u16x8*)(Kz + hh * HSTR + (size_t)gj * 64 + kd0 + 8);
      }
      if (tid < 16) {
        const int gj2 = j1 - 1 + k2r;
#pragma unroll
        for (int hh = 0; hh < 2; ++hh) {
          u16x8 a = {};
          if (gj2 < N_)
            a = *(const u16x8*)(Kz + hh * HSTR + (size_t)gj2 * 64 + k2d);
          kreg2[hh] = a;
        }
      }
#pragma unroll
      for (int hh = 0; hh < 2; ++hh)
#pragma unroll
        for (int hf = 0; hf < 2; ++hf)
          vreg[2 * hh + hf] = *(const u16x8*)(Vz + hh * HSTR + (size_t)vd * 1024 +
                                              j1 + vc0 + (hf << 3));
    }

    // ---- phase 3: swapped conv-QK^T: racc[nt] cols=qr, rows=k-sub ----
    f32x4 racc[4] = {};
    __builtin_amdgcn_s_setprio(1);
#pragma unroll
    for (int c = 0; c < 3; ++c) {
#pragma unroll
      for (int dh = 0; dh < 2; ++dh) {
        const bf16x8 bq = qtf[c][dh];
#pragma unroll
        for (int nt = 0; nt < 4; ++nt) {
          const bf16x8 ak =
              *(const bf16x8*)&Ks[h][(nt << 4) + lr + c][(dh << 5) + lk];
          racc[nt] =
              __builtin_amdgcn_mfma_f32_16x16x32_bf16(ak, bq, racc[nt], 0, 0, 0);
        }
      }
    }
    __builtin_amdgcn_s_setprio(0);

    // ---- phase 4: per-lane online softmax (column qr = mt*16+lr) ----
    float alpha;
    {
      float pmax = racc[0][0];
#pragma unroll
      for (int nt = 0; nt < 4; ++nt)
#pragma unroll
        for (int q = 0; q < 4; ++q) pmax = fmaxf(pmax, racc[nt][q]);
      pmax = fmaxf(pmax, __shfl_xor(pmax, 16));
      pmax = fmaxf(pmax, __shfl_xor(pmax, 32));
      const float mn = fmaxf(mreg, pmax);
      alpha = __expf(mreg - mn);
      mreg = mn;
      float rs = 0.f;
#pragma unroll
      for (int nt = 0; nt < 4; ++nt)
#pragma unroll
        for (int q = 0; q < 4; ++q) {
          const float p = __expf(racc[nt][q] - mn);
          racc[nt][q] = p;
          rs += p;
        }
      rs += __shfl_xor(rs, 16);
      rs += __shfl_xor(rs, 32);
      lreg = lreg * alpha + rs;
      // wave-private P~ store: row qr-sub = lr, k = 16nt+4lg+q (b64 packed)
#pragma unroll
      for (int nt = 0; nt < 4; ++nt) {
        ushort4 pw;
        pw.x = f2bf(racc[nt][0]); pw.y = f2bf(racc[nt][1]);
        pw.z = f2bf(racc[nt][2]); pw.w = f2bf(racc[nt][3]);
        *(ushort4*)&PtW[(size_t)lr * 72 + (nt << 4) + (lg << 2)] = pw;
      }
    }

    // ---- phase 5: PV (both v-heads), alpha via intra-wave shfl ----
    {
      float a4[4];
#pragma unroll
      for (int q = 0; q < 4; ++q)
        a4[q] = __shfl(alpha, (lg << 4) | ((lg << 2) + q));
#pragma unroll
      for (int k2 = 0; k2 < 2; ++k2)
#pragma unroll
        for (int nt = 0; nt < 4; ++nt)
#pragma unroll
          for (int q = 0; q < 4; ++q) acc[k2][nt][q] *= a4[q];
      bf16x8 paf[2];
      paf[0] = *(const bf16x8*)&PtW[(size_t)lr * 72 + lk];
      paf[1] = *(const bf16x8*)&PtW[(size_t)lr * 72 + 32 + lk];
      __builtin_amdgcn_s_setprio(1);
#pragma unroll
      for (int kj = 0; kj < 2; ++kj)
#pragma unroll
        for (int nt = 0; nt < 4; ++nt) {
#pragma unroll
          for (int k2 = 0; k2 < 2; ++k2) {
            const bf16x8 bv =
                *(const bf16x8*)&Vs[k2][(nt << 4) + lr][(kj << 5) + lk];
            acc[k2][nt] = __builtin_amdgcn_mfma_f32_16x16x32_bf16(
                paf[kj], bv, acc[k2][nt], 0, 0, 0);
          }
        }
      __builtin_amdgcn_s_setprio(0);
    }
    __syncthreads();  // B3 (protects Ks/Vs for next staging)
  }

  // ---- epilogue: O_k = sum_h hm[h,k]/l_h * A_hk ----
  if (lg == 0) lsum[h][(mt << 4) + lr] = lreg;
  __syncthreads();

  const float mw0 = hm[(g * 2 + h) * 2 + 0];
  const float mw1 = hm[(g * 2 + h) * 2 + 1];
  float* Os = (float*)&Ks[0][0][0];  // [2k][32 rows][68]
  if (h == 1) {
#pragma unroll
    for (int q = 0; q < 4; ++q) {
      const int row = (mt << 4) + (lg << 2) + q;
      const float f0 = mw0 / lsum[1][row];
      const float f1 = mw1 / lsum[1][row];
#pragma unroll
      for (int nt = 0; nt < 4; ++nt) {
        Os[(size_t)(0 * 32 + row) * 68 + (nt << 4) + lr] = acc[0][nt][q] * f0;
        Os[(size_t)(1 * 32 + row) * 68 + (nt << 4) + lr] = acc[1][nt][q] * f1;
      }
    }
  }
  __syncthreads();
  if (h == 0) {
#pragma unroll
    for (int q = 0; q < 4; ++q) {
      const int row = (mt << 4) + (lg << 2) + q;
      const int gi = i0 + row;
      const float f0 = mw0 / lsum[0][row];
      const float f1 = mw1 / lsum[0][row];
#pragma unroll
      for (int nt = 0; nt < 4; ++nt) {
        const float v0 =
            acc[0][nt][q] * f0 + Os[(size_t)(0 * 32 + row) * 68 + (nt << 4) + lr];
        const float v1 =
            acc[1][nt][q] * f1 + Os[(size_t)(1 * 32 + row) * 68 + (nt << 4) + lr];
        pvout[(size_t)(bb * N_ + gi) * C_ + (2 * g + 0) * 64 + (nt << 4) + lr] = v0;
        pvout[(size_t)(bb * N_ + gi) * C_ + (2 * g + 1) * 64 + (nt << 4) + lr] = v1;
      }
    }
  }
}

extern "C" void kernel_launch(void* const* d_in, const int* in_sizes, int n_in,
                              void* d_out, int out_size, void* d_ws, size_t ws_size,
                              hipStream_t stream) {
  const float* query = (const float*)d_in[0];
  const float* key   = (const float*)d_in[1];
  const float* value = (const float*)d_in[2];
  const float* Wq = (const float*)d_in[3];
  const float* bq = (const float*)d_in[4];
  const float* Wk = (const float*)d_in[5];
  const float* bk = (const float*)d_in[6];
  const float* Wv = (const float*)d_in[7];
  const float* bv = (const float*)d_in[8];
  const float* cw = (const float*)d_in[9];
  const float* hm = (const float*)d_in[10];
  const float* Wo = (const float*)d_in[11];
  const float* bo = (const float*)d_in[12];
  float* out = (float*)d_out;

  char* ws = (char*)d_ws;
  const size_t SZ_BF = (size_t)B_ * H_ * N_ * 64 * 2;  // 12,582,912 B
  unsigned short* Qb = (unsigned short*)ws;
  unsigned short* Kb = (unsigned short*)(ws + SZ_BF);
  unsigned short* Vt = (unsigned short*)(ws + 2 * SZ_BF);  // (B,H,D,N)
  float* pvout = (float*)(ws + 3 * SZ_BF);                 // 25,165,824 B

  const dim3 blk(256);
  proj3<<<dim3(1152), blk, 0, stream>>>(query, key, value, Wq, Wk, Wv, bq, bk, bv,
                                        Qb, Kb, Vt);
  fused_attn<<<dim3(1536), blk, 0, stream>>>(Qb, Kb, Vt, cw, hm, pvout);
  oproj<<<dim3(384), blk, 0, stream>>>(pvout, Wo, bo, out);
}

// Round 8
// 229.377 us; speedup vs baseline: 6.5326x; 1.0132x over previous
//
#include <hip/hip_runtime.h>
#include <stdint.h>

#define B_ 8
#define N_ 1024
#define C_ 768
#define H_ 12
#define G_ 6
#define QBLK 32
#define KSTEP 64
#define NQT 32   // 1024/32
#define NKS 16   // 1024/64

typedef __attribute__((ext_vector_type(8))) short bf16x8;
typedef __attribute__((ext_vector_type(8))) unsigned short u16x8;
typedef __attribute__((ext_vector_type(4))) float f32x4;

__device__ __forceinline__ float bf2f(unsigned short u) {
  return __uint_as_float(((unsigned)u) << 16);
}
__device__ __forceinline__ unsigned short f2bf(float f) {
  unsigned x = __float_as_uint(f);
  unsigned r = x + 0x7fffu + ((x >> 16) & 1u);  // RNE
  return (unsigned short)(r >> 16);
}

// ---------------- fp32 -> bf16 conversion (streaming) ----------------------
__global__ __launch_bounds__(256) void cvtX(
    const float* __restrict__ q, const float* __restrict__ k,
    const float* __restrict__ v, unsigned short* __restrict__ dst) {
  const float* src = (blockIdx.y == 0) ? q : (blockIdx.y == 1) ? k : v;
  unsigned short* d = dst + (size_t)blockIdx.y * ((size_t)B_ * N_ * C_);
  const size_t idx = ((size_t)blockIdx.x * 256 + threadIdx.x) * 8;
  const float4 f0 = *(const float4*)(src + idx);
  const float4 f1 = *(const float4*)(src + idx + 4);
  u16x8 o;
  o[0] = f2bf(f0.x); o[1] = f2bf(f0.y); o[2] = f2bf(f0.z); o[3] = f2bf(f0.w);
  o[4] = f2bf(f1.x); o[5] = f2bf(f1.y); o[6] = f2bf(f1.z); o[7] = f2bf(f1.w);
  *(u16x8*)(d + idx) = o;
}

__global__ __launch_bounds__(256) void cvtW(
    const float* __restrict__ wq, const float* __restrict__ wk,
    const float* __restrict__ wv, const float* __restrict__ wo,
    unsigned short* __restrict__ dst) {
  const float* src = (blockIdx.y == 0)   ? wq
                     : (blockIdx.y == 1) ? wk
                     : (blockIdx.y == 2) ? wv
                                         : wo;
  unsigned short* d = dst + (size_t)blockIdx.y * ((size_t)C_ * C_);
  const size_t idx = ((size_t)blockIdx.x * 256 + threadIdx.x) * 8;
  const float4 f0 = *(const float4*)(src + idx);
  const float4 f1 = *(const float4*)(src + idx + 4);
  u16x8 o;
  o[0] = f2bf(f0.x); o[1] = f2bf(f0.y); o[2] = f2bf(f0.z); o[3] = f2bf(f0.w);
  o[4] = f2bf(f1.x); o[5] = f2bf(f1.y); o[6] = f2bf(f1.z); o[7] = f2bf(f1.w);
  *(u16x8*)(d + idx) = o;
}

// ================= bf16 MFMA GEMM body: out = X @ W^T + bias ===============
// 128x128 tile, BK=32, 4 waves, reg-prefetch of next K-step.
// MODE 0: fp32 out [M][768]. MODE 1: bf16 (B,H,N,D). MODE 2: bf16 (B,H,D,N).
// LDS passed in (shared across template instantiations).
template <int MODE>
__device__ __forceinline__ void gemm_bf16(
    const unsigned short* __restrict__ X, const unsigned short* __restrict__ W,
    const float* __restrict__ bias, void* __restrict__ out, int row0, int col0,
    unsigned short* __restrict__ As /*[128][40]*/,
    unsigned short* __restrict__ Bs /*[128][40]*/) {
  const int tid = threadIdx.x;
  const int wid = tid >> 6, lane = tid & 63;
  const int lr = lane & 15, lk = (lane >> 4) << 3;
  const int qrow = (lane >> 4) << 2;
  const int wr = (wid & 1) << 6, wc = (wid >> 1) << 6;
  const int sr = tid & 127, sk = (tid >> 7) << 4;
  const unsigned short* Xr = X + (size_t)(row0 + sr) * C_ + sk;
  const unsigned short* Wr = W + (size_t)(col0 + sr) * C_ + sk;
  u16x8 pa0 = *(const u16x8*)(Xr);
  u16x8 pa1 = *(const u16x8*)(Xr + 8);
  u16x8 pb0 = *(const u16x8*)(Wr);
  u16x8 pb1 = *(const u16x8*)(Wr + 8);
  f32x4 acc[4][4] = {};
  for (int k0 = 0; k0 < C_; k0 += 32) {
    *(u16x8*)&As[sr * 40 + sk] = pa0;
    *(u16x8*)&As[sr * 40 + sk + 8] = pa1;
    *(u16x8*)&Bs[sr * 40 + sk] = pb0;
    *(u16x8*)&Bs[sr * 40 + sk + 8] = pb1;
    __syncthreads();
    if (k0 + 32 < C_) {
      pa0 = *(const u16x8*)(Xr + k0 + 32);
      pa1 = *(const u16x8*)(Xr + k0 + 40);
      pb0 = *(const u16x8*)(Wr + k0 + 32);
      pb1 = *(const u16x8*)(Wr + k0 + 40);
    }
    bf16x8 af[4], bg[4];
#pragma unroll
    for (int m = 0; m < 4; ++m)
      af[m] = *(const bf16x8*)&As[(wr + (m << 4) + lr) * 40 + lk];
#pragma unroll
    for (int n = 0; n < 4; ++n)
      bg[n] = *(const bf16x8*)&Bs[(wc + (n << 4) + lr) * 40 + lk];
#pragma unroll
    for (int m = 0; m < 4; ++m)
#pragma unroll
      for (int n = 0; n < 4; ++n)
        acc[m][n] = __builtin_amdgcn_mfma_f32_16x16x32_bf16(af[m], bg[n],
                                                            acc[m][n], 0, 0, 0);
    __syncthreads();
  }
#pragma unroll
  for (int m = 0; m < 4; ++m) {
#pragma unroll
    for (int n = 0; n < 4; ++n) {
      const int colc = col0 + wc + (n << 4) + lr;
      const float bv = bias[colc];
      if (MODE == 2) {
        const int r0 = row0 + wr + (m << 4) + qrow;
        const int bb = r0 >> 10, nn0 = r0 & 1023;
        const int hh = colc >> 6, dd = colc & 63;
        ushort4 pk;
        pk.x = f2bf(acc[m][n][0] + bv);
        pk.y = f2bf(acc[m][n][1] + bv);
        pk.z = f2bf(acc[m][n][2] + bv);
        pk.w = f2bf(acc[m][n][3] + bv);
        *(ushort4*)&((unsigned short*)out)[(((size_t)(bb * H_ + hh) << 6) + dd)
                                               * 1024 + nn0] = pk;
      } else {
#pragma unroll
        for (int q = 0; q < 4; ++q) {
          const int r = row0 + wr + (m << 4) + qrow + q;
          const float v = acc[m][n][q] + bv;
          if (MODE == 0) {
            ((float*)out)[(size_t)r * C_ + colc] = v;
          } else {
            const int bb = r >> 10, nn = r & 1023;
            const int hh = colc >> 6, dd = colc & 63;
            ((unsigned short*)out)[(((size_t)(bb * H_ + hh) << 10) + nn) * 64 +
                                   dd] = f2bf(v);
          }
        }
      }
    }
  }
}

__global__ __launch_bounds__(256) void proj3(
    const unsigned short* __restrict__ Xb, const unsigned short* __restrict__ Wb,
    const float* __restrict__ bq, const float* __restrict__ bk,
    const float* __restrict__ bv, unsigned short* Qb, unsigned short* Kb,
    unsigned short* Vt) {
  __shared__ __align__(16) unsigned short As[128 * 40];
  __shared__ __align__(16) unsigned short Bs[128 * 40];
  const int wg = blockIdx.x;
  const int nid = (wg & 7) * 144 + (wg >> 3);
  const int x = nid % 6, y = (nid / 6) & 63, z = nid / 384;
  const unsigned short* X = Xb + (size_t)z * B_ * N_ * C_;
  const unsigned short* W = Wb + (size_t)z * C_ * C_;
  if (z == 0)
    gemm_bf16<1>(X, W, bq, Qb, y << 7, x << 7, As, Bs);
  else if (z == 1)
    gemm_bf16<1>(X, W, bk, Kb, y << 7, x << 7, As, Bs);
  else
    gemm_bf16<2>(X, W, bv, Vt, y << 7, x << 7, As, Bs);
}

__global__ __launch_bounds__(256) void oproj(
    const unsigned short* __restrict__ X, const unsigned short* __restrict__ Wb,
    const float* __restrict__ bo, float* __restrict__ out) {
  __shared__ __align__(16) unsigned short As[128 * 40];
  __shared__ __align__(16) unsigned short Bs[128 * 40];
  const int wg = blockIdx.x;
  const int nid = (wg & 7) * 48 + (wg >> 3);
  const int x = nid % 6, y = nid / 6;
  gemm_bf16<0>(X, Wb + (size_t)3 * C_ * C_, bo, out, y << 7, x << 7, As, Bs);
}

// ============ fused: conv-folded QK^T (swapped) -> reg softmax -> PV =======
__global__ __launch_bounds__(256, 3) void fused_attn(
    const unsigned short* __restrict__ Qb, const unsigned short* __restrict__ Kb,
    const unsigned short* __restrict__ Vt, const float* __restrict__ cw,
    const float* __restrict__ hm, unsigned short* __restrict__ pvout) {
  __shared__ __align__(16) unsigned short Ks[2][66][72];   // row r <-> j0-1+r
  __shared__ __align__(16) unsigned short Vs[2][64][72];   // [h][d][c]
  __shared__ __align__(16) unsigned short QPt[4896];       // Q stage / per-wave Pt
  __shared__ float lsum[2][32];

  const int wg = blockIdx.x;  // 1536 = 8 * 192
  const int nid = (wg & 7) * 192 + (wg >> 3);
  const int qt = nid & 31;
  const int bg = nid >> 5;
  const int g = bg % G_, bb = bg / G_;
  const int i0 = qt << 5;

  const int tid = threadIdx.x;
  const int wid = tid >> 6, lane = tid & 63;
  const int lr = lane & 15, lg = lane >> 4;
  const int lk = lg << 3;

  const int h = wid >> 1, mt = wid & 1;  // wave role: (head, q-row tile)

  const size_t HSTR = (size_t)N_ * 64;
  const unsigned short* Qz = Qb + (size_t)(bb * H_ + 2 * g) * HSTR;
  const unsigned short* Kz = Kb + (size_t)(bb * H_ + 2 * g) * HSTR;
  const unsigned short* Vz = Vt + (size_t)(bb * H_ + 2 * g) * HSTR;  // [h][d][n]

  // staging roles
  const int krow = tid >> 2, kd0 = (tid & 3) << 4;        // K rows 0..63
  const int k2r = 64 + (tid >> 3), k2d = (tid & 7) << 3;  // halo rows (tid<16)
  const int vd = tid >> 2, vc0 = (tid & 3) << 4;          // V^T rows

  u16x8 kreg[4], vreg[4];
  u16x8 kreg2[2];

  // ---- prefetch step 0 ----
  {
    const int gj = -1 + krow;
#pragma unroll
    for (int hh = 0; hh < 2; ++hh) {
      u16x8 a = {}, b = {};
      if (gj >= 0) {
        a = *(const u16x8*)(Kz + hh * HSTR + (size_t)gj * 64 + kd0);
        b = *(const u16x8*)(Kz + hh * HSTR + (size_t)gj * 64 + kd0 + 8);
      }
      kreg[2 * hh] = a; kreg[2 * hh + 1] = b;
    }
    if (tid < 16) {
      const int gj2 = -1 + k2r;  // 63 or 64
#pragma unroll
      for (int hh = 0; hh < 2; ++hh)
        kreg2[hh] = *(const u16x8*)(Kz + hh * HSTR + (size_t)gj2 * 64 + k2d);
    }
#pragma unroll
    for (int hh = 0; hh < 2; ++hh)
#pragma unroll
      for (int hf = 0; hf < 2; ++hf)
        vreg[2 * hh + hf] =
            *(const u16x8*)(Vz + hh * HSTR + (size_t)vd * 1024 + vc0 + (hf << 3));
  }

  // ---- stage Q rows i0-1 .. i0+32 (34 rows, OOB -> 0) into QPt ----
  {
    const int r = tid >> 3, d0 = (tid & 7) << 3;
    {
      const int gi = i0 - 1 + r;
#pragma unroll
      for (int hh = 0; hh < 2; ++hh) {
        u16x8 qv = {};
        if (gi >= 0 && gi < N_)
          qv = *(const u16x8*)(Qz + hh * HSTR + (size_t)gi * 64 + d0);
        *(u16x8*)&QPt[((size_t)(hh * 34 + r)) * 72 + d0] = qv;
      }
    }
    if (tid < 16) {
      const int r2 = 32 + (tid >> 3);
      const int gi = i0 - 1 + r2;
#pragma unroll
      for (int hh = 0; hh < 2; ++hh) {
        u16x8 qv = {};
        if (gi < N_) qv = *(const u16x8*)(Qz + hh * HSTR + (size_t)gi * 64 + d0);
        *(u16x8*)&QPt[((size_t)(hh * 34 + r2)) * 72 + d0] = qv;
      }
    }
  }
  __syncthreads();  // Q staged

  // ---- extract Qtilde fragments (B-operand; rows (mt<<4)+lr) ----
  bf16x8 qtf[3][2];  // [c][dh]
  {
    float wc3[3][3];
#pragma unroll
    for (int a = 0; a < 3; ++a)
#pragma unroll
      for (int c = 0; c < 3; ++c)
        wc3[a][c] = cw[(2 * g + h) * 9 + a * 3 + c] * 0.125f;
    const int ribase = (mt << 4) + lr;
#pragma unroll
    for (int dh = 0; dh < 2; ++dh) {
      const u16x8 qa = *(const u16x8*)&QPt[((size_t)(h * 34 + ribase + 0)) * 72 +
                                           (dh << 5) + lk];
      const u16x8 qb = *(const u16x8*)&QPt[((size_t)(h * 34 + ribase + 1)) * 72 +
                                           (dh << 5) + lk];
      const u16x8 qc = *(const u16x8*)&QPt[((size_t)(h * 34 + ribase + 2)) * 72 +
                                           (dh << 5) + lk];
#pragma unroll
      for (int c = 0; c < 3; ++c) {
#pragma unroll
        for (int e = 0; e < 8; ++e) {
          const float v = bf2f(qa[e]) * wc3[0][c] + bf2f(qb[e]) * wc3[1][c] +
                          bf2f(qc[e]) * wc3[2][c];
          qtf[c][dh][e] = (short)f2bf(v);
        }
      }
    }
  }
  // (B1 of step 0 fences all waves' Q reads before first Pt overwrite.)

  unsigned short* PtW = &QPt[(size_t)wid * 16 * 72];  // wave-private [16][72]

  float mreg = -3.0e38f, lreg = 0.f;  // for q-column qr = mt*16+lr
  f32x4 acc[2][4] = {};               // [v-head k][nt(d)]

  for (int s = 0; s < NKS; ++s) {
    // ---- phase 1: write staged K/V regs to LDS ----
    *(u16x8*)&Ks[0][krow][kd0] = kreg[0];
    *(u16x8*)&Ks[0][krow][kd0 + 8] = kreg[1];
    *(u16x8*)&Ks[1][krow][kd0] = kreg[2];
    *(u16x8*)&Ks[1][krow][kd0 + 8] = kreg[3];
    if (tid < 16) {
      *(u16x8*)&Ks[0][k2r][k2d] = kreg2[0];
      *(u16x8*)&Ks[1][k2r][k2d] = kreg2[1];
    }
    *(u16x8*)&Vs[0][vd][vc0] = vreg[0];
    *(u16x8*)&Vs[0][vd][vc0 + 8] = vreg[1];
    *(u16x8*)&Vs[1][vd][vc0] = vreg[2];
    *(u16x8*)&Vs[1][vd][vc0 + 8] = vreg[3];
    __syncthreads();  // B1

    // ---- phase 2: issue loads for step s+1 ----
    if (s + 1 < NKS) {
      const int j1 = (s + 1) << 6;
      const int gj = j1 - 1 + krow;
#pragma unroll
      for (int hh = 0; hh < 2; ++hh) {
        kreg[2 * hh] = *(const u16x8*)(Kz + hh * HSTR + (size_t)gj * 64 + kd0);
        kreg[2 * hh + 1] =
            *(const u16x8*)(Kz + hh * HSTR + (size_t)gj * 64 + kd0 + 8);
      }
      if (tid < 16) {
        const int gj2 = j1 - 1 + k2r;
#pragma unroll
        for (int hh = 0; hh < 2; ++hh) {
          u16x8 a = {};
          if (gj2 < N_)
            a = *(const u16x8*)(Kz + hh * HSTR + (size_t)gj2 * 64 + k2d);
          kreg2[hh] = a;
        }
      }
#pragma unroll
      for (int hh = 0; hh < 2; ++hh)
#pragma unroll
        for (int hf = 0; hf < 2; ++hf)
          vreg[2 * hh + hf] = *(const u16x8*)(Vz + hh * HSTR + (size_t)vd * 1024 +
                                              j1 + vc0 + (hf << 3));
    }

    // ---- phase 3: swapped conv-QK^T: racc[nt] cols=qr, rows=k-sub ----
    f32x4 racc[4] = {};
    __builtin_amdgcn_s_setprio(1);
#pragma unroll
    for (int c = 0; c < 3; ++c) {
#pragma unroll
      for (int dh = 0; dh < 2; ++dh) {
        const bf16x8 bq = qtf[c][dh];
#pragma unroll
        for (int nt = 0; nt < 4; ++nt) {
          const bf16x8 ak =
              *(const bf16x8*)&Ks[h][(nt << 4) + lr + c][(dh << 5) + lk];
          racc[nt] =
              __builtin_amdgcn_mfma_f32_16x16x32_bf16(ak, bq, racc[nt], 0, 0, 0);
        }
      }
    }
    __builtin_amdgcn_s_setprio(0);

    // ---- phase 4: per-lane online softmax (column qr = mt*16+lr) ----
    float alpha;
    {
      float pmax = racc[0][0];
#pragma unroll
      for (int nt = 0; nt < 4; ++nt)
#pragma unroll
        for (int q = 0; q < 4; ++q) pmax = fmaxf(pmax, racc[nt][q]);
      pmax = fmaxf(pmax, __shfl_xor(pmax, 16));
      pmax = fmaxf(pmax, __shfl_xor(pmax, 32));
      const float mn = fmaxf(mreg, pmax);
      alpha = __expf(mreg - mn);
      mreg = mn;
      float rs = 0.f;
#pragma unroll
      for (int nt = 0; nt < 4; ++nt)
#pragma unroll
        for (int q = 0; q < 4; ++q) {
          const float p = __expf(racc[nt][q] - mn);
          racc[nt][q] = p;
          rs += p;
        }
      rs += __shfl_xor(rs, 16);
      rs += __shfl_xor(rs, 32);
      lreg = lreg * alpha + rs;
      // wave-private P~ store: row qr-sub = lr, k = 16nt+4lg+q (b64 packed)
#pragma unroll
      for (int nt = 0; nt < 4; ++nt) {
        ushort4 pw;
        pw.x = f2bf(racc[nt][0]); pw.y = f2bf(racc[nt][1]);
        pw.z = f2bf(racc[nt][2]); pw.w = f2bf(racc[nt][3]);
        *(ushort4*)&PtW[(size_t)lr * 72 + (nt << 4) + (lg << 2)] = pw;
      }
    }

    // ---- phase 5: PV (both v-heads), alpha via intra-wave shfl ----
    {
      float a4[4];
#pragma unroll
      for (int q = 0; q < 4; ++q)
        a4[q] = __shfl(alpha, (lg << 4) | ((lg << 2) + q));
#pragma unroll
      for (int k2 = 0; k2 < 2; ++k2)
#pragma unroll
        for (int nt = 0; nt < 4; ++nt)
#pragma unroll
          for (int q = 0; q < 4; ++q) acc[k2][nt][q] *= a4[q];
      bf16x8 paf[2];
      paf[0] = *(const bf16x8*)&PtW[(size_t)lr * 72 + lk];
      paf[1] = *(const bf16x8*)&PtW[(size_t)lr * 72 + 32 + lk];
      __builtin_amdgcn_s_setprio(1);
#pragma unroll
      for (int kj = 0; kj < 2; ++kj)
#pragma unroll
        for (int nt = 0; nt < 4; ++nt) {
#pragma unroll
          for (int k2 = 0; k2 < 2; ++k2) {
            const bf16x8 bv =
                *(const bf16x8*)&Vs[k2][(nt << 4) + lr][(kj << 5) + lk];
            acc[k2][nt] = __builtin_amdgcn_mfma_f32_16x16x32_bf16(
                paf[kj], bv, acc[k2][nt], 0, 0, 0);
          }
        }
      __builtin_amdgcn_s_setprio(0);
    }
    __syncthreads();  // B3 (protects Ks/Vs for next staging)
  }

  // ---- epilogue: O_k = sum_h hm[h,k]/l_h * A_hk ----
  if (lg == 0) lsum[h][(mt << 4) + lr] = lreg;
  __syncthreads();

  const float mw0 = hm[(g * 2 + h) * 2 + 0];
  const float mw1 = hm[(g * 2 + h) * 2 + 1];
  float* Os = (float*)&Ks[0][0][0];  // [2k][32 rows][68]
  if (h == 1) {
#pragma unroll
    for (int q = 0; q < 4; ++q) {
      const int row = (mt << 4) + (lg << 2) + q;
      const float f0 = mw0 / lsum[1][row];
      const float f1 = mw1 / lsum[1][row];
#pragma unroll
      for (int nt = 0; nt < 4; ++nt) {
        Os[(size_t)(0 * 32 + row) * 68 + (nt << 4) + lr] = acc[0][nt][q] * f0;
        Os[(size_t)(1 * 32 + row) * 68 + (nt << 4) + lr] = acc[1][nt][q] * f1;
      }
    }
  }
  __syncthreads();
  if (h == 0) {
#pragma unroll
    for (int q = 0; q < 4; ++q) {
      const int row = (mt << 4) + (lg << 2) + q;
      const int gi = i0 + row;
      const float f0 = mw0 / lsum[0][row];
      const float f1 = mw1 / lsum[0][row];
#pragma unroll
      for (int nt = 0; nt < 4; ++nt) {
        const float v0 =
            acc[0][nt][q] * f0 + Os[(size_t)(0 * 32 + row) * 68 + (nt << 4) + lr];
        const float v1 =
            acc[1][nt][q] * f1 + Os[(size_t)(1 * 32 + row) * 68 + (nt << 4) + lr];
        pvout[(size_t)(bb * N_ + gi) * C_ + (2 * g + 0) * 64 + (nt << 4) + lr] =
            f2bf(v0);
        pvout[(size_t)(bb * N_ + gi) * C_ + (2 * g + 1) * 64 + (nt << 4) + lr] =
            f2bf(v1);
      }
    }
  }
}

extern "C" void kernel_launch(void* const* d_in, const int* in_sizes, int n_in,
                              void* d_out, int out_size, void* d_ws, size_t ws_size,
                              hipStream_t stream) {
  const float* query = (const float*)d_in[0];
  const float* key   = (const float*)d_in[1];
  const float* value = (const float*)d_in[2];
  const float* Wq = (const float*)d_in[3];
  const float* bq = (const float*)d_in[4];
  const float* Wk = (const float*)d_in[5];
  const float* bk = (const float*)d_in[6];
  const float* Wv = (const float*)d_in[7];
  const float* bv = (const float*)d_in[8];
  const float* cw = (const float*)d_in[9];
  const float* hm = (const float*)d_in[10];
  const float* Wo = (const float*)d_in[11];
  const float* bo = (const float*)d_in[12];
  float* out = (float*)d_out;

  char* ws = (char*)d_ws;
  const size_t SZ_BF = (size_t)B_ * H_ * N_ * 64 * 2;  // 12,582,912 B
  unsigned short* Qb = (unsigned short*)ws;
  unsigned short* Kb = (unsigned short*)(ws + SZ_BF);
  unsigned short* Vt = (unsigned short*)(ws + 2 * SZ_BF);   // (B,H,D,N)
  unsigned short* pvb = (unsigned short*)(ws + 3 * SZ_BF);  // bf16 (B,N,C)
  unsigned short* Xb = (unsigned short*)(ws + 4 * SZ_BF);   // q,k,v bf16
  unsigned short* Wb = (unsigned short*)(ws + 7 * SZ_BF);   // Wq,Wk,Wv,Wo bf16

  const dim3 blk(256);
  cvtX<<<dim3(3072, 3), blk, 0, stream>>>(query, key, value, Xb);
  cvtW<<<dim3(288, 4), blk, 0, stream>>>(Wq, Wk, Wv, Wo, Wb);
  proj3<<<dim3(1152), blk, 0, stream>>>(Xb, Wb, bq, bk, bv, Qb, Kb, Vt);
  fused_attn<<<dim3(1536), blk, 0, stream>>>(Qb, Kb, Vt, cw, hm, pvb);
  oproj<<<dim3(384), blk, 0, stream>>>(pvb, Wb, bo, out);
}

// Round 10
// 223.289 us; speedup vs baseline: 6.7108x; 1.0273x over previous
//
#include <hip/hip_runtime.h>
#include <stdint.h>

#define B_ 8
#define N_ 1024
#define C_ 768
#define H_ 12
#define G_ 6
#define QBLK 32
#define KSTEP 64
#define NQT 32   // 1024/32
#define NKS 16   // 1024/64

typedef __attribute__((ext_vector_type(8))) short bf16x8;
typedef __attribute__((ext_vector_type(8))) unsigned short u16x8;
typedef __attribute__((ext_vector_type(4))) float f32x4;

__device__ __forceinline__ float bf2f(unsigned short u) {
  return __uint_as_float(((unsigned)u) << 16);
}
__device__ __forceinline__ unsigned short f2bf(float f) {
  unsigned x = __float_as_uint(f);
  unsigned r = x + 0x7fffu + ((x >> 16) & 1u);  // RNE
  return (unsigned short)(r >> 16);
}

// ---------------- fp32 -> bf16 conversion (streaming) ----------------------
__global__ __launch_bounds__(256) void cvtX(
    const float* __restrict__ q, const float* __restrict__ k,
    const float* __restrict__ v, unsigned short* __restrict__ dst) {
  const float* src = (blockIdx.y == 0) ? q : (blockIdx.y == 1) ? k : v;
  unsigned short* d = dst + (size_t)blockIdx.y * ((size_t)B_ * N_ * C_);
  const size_t idx = ((size_t)blockIdx.x * 256 + threadIdx.x) * 8;
  const float4 f0 = *(const float4*)(src + idx);
  const float4 f1 = *(const float4*)(src + idx + 4);
  u16x8 o;
  o[0] = f2bf(f0.x); o[1] = f2bf(f0.y); o[2] = f2bf(f0.z); o[3] = f2bf(f0.w);
  o[4] = f2bf(f1.x); o[5] = f2bf(f1.y); o[6] = f2bf(f1.z); o[7] = f2bf(f1.w);
  *(u16x8*)(d + idx) = o;
}

__global__ __launch_bounds__(256) void cvtW(
    const float* __restrict__ wq, const float* __restrict__ wk,
    const float* __restrict__ wv, const float* __restrict__ wo,
    unsigned short* __restrict__ dst) {
  const float* src = (blockIdx.y == 0)   ? wq
                     : (blockIdx.y == 1) ? wk
                     : (blockIdx.y == 2) ? wv
                                         : wo;
  unsigned short* d = dst + (size_t)blockIdx.y * ((size_t)C_ * C_);
  const size_t idx = ((size_t)blockIdx.x * 256 + threadIdx.x) * 8;
  const float4 f0 = *(const float4*)(src + idx);
  const float4 f1 = *(const float4*)(src + idx + 4);
  u16x8 o;
  o[0] = f2bf(f0.x); o[1] = f2bf(f0.y); o[2] = f2bf(f0.z); o[3] = f2bf(f0.w);
  o[4] = f2bf(f1.x); o[5] = f2bf(f1.y); o[6] = f2bf(f1.z); o[7] = f2bf(f1.w);
  *(u16x8*)(d + idx) = o;
}

// ================= bf16 MFMA GEMM body: out = X @ W^T + bias ===============
template <int MODE>
__device__ __forceinline__ void gemm_bf16(
    const unsigned short* __restrict__ X, const unsigned short* __restrict__ W,
    const float* __restrict__ bias, void* __restrict__ out, int row0, int col0,
    unsigned short* __restrict__ As /*[128][40]*/,
    unsigned short* __restrict__ Bs /*[128][40]*/) {
  const int tid = threadIdx.x;
  const int wid = tid >> 6, lane = tid & 63;
  const int lr = lane & 15, lk = (lane >> 4) << 3;
  const int qrow = (lane >> 4) << 2;
  const int wr = (wid & 1) << 6, wc = (wid >> 1) << 6;
  const int sr = tid & 127, sk = (tid >> 7) << 4;
  const unsigned short* Xr = X + (size_t)(row0 + sr) * C_ + sk;
  const unsigned short* Wr = W + (size_t)(col0 + sr) * C_ + sk;
  u16x8 pa0 = *(const u16x8*)(Xr);
  u16x8 pa1 = *(const u16x8*)(Xr + 8);
  u16x8 pb0 = *(const u16x8*)(Wr);
  u16x8 pb1 = *(const u16x8*)(Wr + 8);
  f32x4 acc[4][4] = {};
  for (int k0 = 0; k0 < C_; k0 += 32) {
    *(u16x8*)&As[sr * 40 + sk] = pa0;
    *(u16x8*)&As[sr * 40 + sk + 8] = pa1;
    *(u16x8*)&Bs[sr * 40 + sk] = pb0;
    *(u16x8*)&Bs[sr * 40 + sk + 8] = pb1;
    __syncthreads();
    if (k0 + 32 < C_) {
      pa0 = *(const u16x8*)(Xr + k0 + 32);
      pa1 = *(const u16x8*)(Xr + k0 + 40);
      pb0 = *(const u16x8*)(Wr + k0 + 32);
      pb1 = *(const u16x8*)(Wr + k0 + 40);
    }
    bf16x8 af[4], bg[4];
#pragma unroll
    for (int m = 0; m < 4; ++m)
      af[m] = *(const bf16x8*)&As[(wr + (m << 4) + lr) * 40 + lk];
#pragma unroll
    for (int n = 0; n < 4; ++n)
      bg[n] = *(const bf16x8*)&Bs[(wc + (n << 4) + lr) * 40 + lk];
#pragma unroll
    for (int m = 0; m < 4; ++m)
#pragma unroll
      for (int n = 0; n < 4; ++n)
        acc[m][n] = __builtin_amdgcn_mfma_f32_16x16x32_bf16(af[m], bg[n],
                                                            acc[m][n], 0, 0, 0);
    __syncthreads();
  }
#pragma unroll
  for (int m = 0; m < 4; ++m) {
#pragma unroll
    for (int n = 0; n < 4; ++n) {
      const int colc = col0 + wc + (n << 4) + lr;
      const float bv = bias[colc];
      if (MODE == 2) {
        const int r0 = row0 + wr + (m << 4) + qrow;
        const int bb = r0 >> 10, nn0 = r0 & 1023;
        const int hh = colc >> 6, dd = colc & 63;
        ushort4 pk;
        pk.x = f2bf(acc[m][n][0] + bv);
        pk.y = f2bf(acc[m][n][1] + bv);
        pk.z = f2bf(acc[m][n][2] + bv);
        pk.w = f2bf(acc[m][n][3] + bv);
        *(ushort4*)&((unsigned short*)out)[(((size_t)(bb * H_ + hh) << 6) + dd)
                                               * 1024 + nn0] = pk;
      } else {
#pragma unroll
        for (int q = 0; q < 4; ++q) {
          const int r = row0 + wr + (m << 4) + qrow + q;
          const float v = acc[m][n][q] + bv;
          if (MODE == 0) {
            ((float*)out)[(size_t)r * C_ + colc] = v;
          } else {
            const int bb = r >> 10, nn = r & 1023;
            const int hh = colc >> 6, dd = colc & 63;
            ((unsigned short*)out)[(((size_t)(bb * H_ + hh) << 10) + nn) * 64 +
                                   dd] = f2bf(v);
          }
        }
      }
    }
  }
}

__global__ __launch_bounds__(256) void proj3(
    const unsigned short* __restrict__ Xb, const unsigned short* __restrict__ Wb,
    const float* __restrict__ bq, const float* __restrict__ bk,
    const float* __restrict__ bv, unsigned short* Qb, unsigned short* Kb,
    unsigned short* Vt) {
  __shared__ __align__(16) unsigned short As[128 * 40];
  __shared__ __align__(16) unsigned short Bs[128 * 40];
  const int wg = blockIdx.x;
  const int nid = (wg & 7) * 144 + (wg >> 3);
  const int x = nid % 6, y = (nid / 6) & 63, z = nid / 384;
  const unsigned short* X = Xb + (size_t)z * B_ * N_ * C_;
  const unsigned short* W = Wb + (size_t)z * C_ * C_;
  if (z == 0)
    gemm_bf16<1>(X, W, bq, Qb, y << 7, x << 7, As, Bs);
  else if (z == 1)
    gemm_bf16<1>(X, W, bk, Kb, y << 7, x << 7, As, Bs);
  else
    gemm_bf16<2>(X, W, bv, Vt, y << 7, x << 7, As, Bs);
}

__global__ __launch_bounds__(256) void oproj(
    const unsigned short* __restrict__ X, const unsigned short* __restrict__ Wb,
    const float* __restrict__ bo, float* __restrict__ out) {
  __shared__ __align__(16) unsigned short As[128 * 40];
  __shared__ __align__(16) unsigned short Bs[128 * 40];
  const int wg = blockIdx.x;
  const int nid = (wg & 7) * 48 + (wg >> 3);
  const int x = nid % 6, y = nid / 6;
  gemm_bf16<0>(X, Wb + (size_t)3 * C_ * C_, bo, out, y << 7, x << 7, As, Bs);
}

// ============ fused: conv-folded QK^T (swapped) -> reg softmax -> PV =======
// LDS layout (one blob, 43,328 B -> 3 blocks/CU):
//   [0)        K: [2 heads][66 rows] x 128 B, XOR-swizzled 16B chunks
//   [16896)    V: [2 heads][64 rows] x 128 B, XOR-swizzled
//   [33280)    QPt: u16 [2][34][72]  (Q stage; later per-wave Pt [4][16][72])
//   [43072)    lsum: f32 [2][32]
// Swizzle: chunk' = chunk ^ (row & 7); chunk = 16B unit within 128 B row.
__global__ __launch_bounds__(256, 3) void fused_attn(
    const unsigned short* __restrict__ Qb, const unsigned short* __restrict__ Kb,
    const unsigned short* __restrict__ Vt, const float* __restrict__ cw,
    const float* __restrict__ hm, unsigned short* __restrict__ pvout) {
  __shared__ __align__(16) unsigned char smem[43328];
  unsigned short* QPt = (unsigned short*)(smem + 33280);
  float* lsum = (float*)(smem + 43072);  // [h][row] = lsum[h*32+row]
#define KBASE(hh) (smem + (size_t)(hh)*8448)
#define VBASE(hh) (smem + 16896 + (size_t)(hh)*8192)

  const int wg = blockIdx.x;  // 1536 = 8 * 192
  const int nid = (wg & 7) * 192 + (wg >> 3);
  const int qt = nid & 31;
  const int bg = nid >> 5;
  const int g = bg % G_, bb = bg / G_;
  const int i0 = qt << 5;

  const int tid = threadIdx.x;
  const int wid = tid >> 6, lane = tid & 63;
  const int lr = lane & 15, lg = lane >> 4;
  const int lk = lg << 3;

  const int h = wid >> 1, mt = wid & 1;  // wave role: (head, q-row tile)

  const size_t HSTR = (size_t)N_ * 64;
  const unsigned short* Qz = Qb + (size_t)(bb * H_ + 2 * g) * HSTR;
  const unsigned short* Kz = Kb + (size_t)(bb * H_ + 2 * g) * HSTR;
  const unsigned short* Vz = Vt + (size_t)(bb * H_ + 2 * g) * HSTR;  // [h][d][n]

  // staging roles
  const int krow = tid >> 2, kd0 = (tid & 3) << 4;        // K rows 0..63
  const int kc0 = (tid & 3) << 1;                         // 16B chunks 0,2,4,6
  const int k2r = 64 + (tid >> 3), k2d = (tid & 7) << 3;  // halo rows (tid<16)
  const int vd = tid >> 2, vc0 = (tid & 3) << 4;          // V^T rows

  u16x8 kreg[4], vreg[4];
  u16x8 kreg2[2];

  // ---- prefetch step 0 ----
  {
    const int gj = -1 + krow;
#pragma unroll
    for (int hh = 0; hh < 2; ++hh) {
      u16x8 a = {}, b = {};
      if (gj >= 0) {
        a = *(const u16x8*)(Kz + hh * HSTR + (size_t)gj * 64 + kd0);
        b = *(const u16x8*)(Kz + hh * HSTR + (size_t)gj * 64 + kd0 + 8);
      }
      kreg[2 * hh] = a; kreg[2 * hh + 1] = b;
    }
    if (tid < 16) {
      const int gj2 = -1 + k2r;  // 63 or 64
#pragma unroll
      for (int hh = 0; hh < 2; ++hh)
        kreg2[hh] = *(const u16x8*)(Kz + hh * HSTR + (size_t)gj2 * 64 + k2d);
    }
#pragma unroll
    for (int hh = 0; hh < 2; ++hh)
#pragma unroll
      for (int hf = 0; hf < 2; ++hf)
        vreg[2 * hh + hf] =
            *(const u16x8*)(Vz + hh * HSTR + (size_t)vd * 1024 + vc0 + (hf << 3));
  }

  // ---- stage Q rows i0-1 .. i0+32 (34 rows, OOB -> 0) into QPt ----
  {
    const int r = tid >> 3, d0 = (tid & 7) << 3;
    {
      const int gi = i0 - 1 + r;
#pragma unroll
      for (int hh = 0; hh < 2; ++hh) {
        u16x8 qv = {};
        if (gi >= 0 && gi < N_)
          qv = *(const u16x8*)(Qz + hh * HSTR + (size_t)gi * 64 + d0);
        *(u16x8*)&QPt[((size_t)(hh * 34 + r)) * 72 + d0] = qv;
      }
    }
    if (tid < 16) {
      const int r2 = 32 + (tid >> 3);
      const int gi = i0 - 1 + r2;
#pragma unroll
      for (int hh = 0; hh < 2; ++hh) {
        u16x8 qv = {};
        if (gi < N_) qv = *(const u16x8*)(Qz + hh * HSTR + (size_t)gi * 64 + d0);
        *(u16x8*)&QPt[((size_t)(hh * 34 + r2)) * 72 + d0] = qv;
      }
    }
  }
  __syncthreads();  // Q staged

  // ---- extract Qtilde fragments (B-operand; rows (mt<<4)+lr) ----
  // weights folded: *0.125 (1/sqrt(D)) and *log2(e) (exp2 domain)
  bf16x8 qtf[3][2];  // [c][dh]
  {
    float wc3[3][3];
#pragma unroll
    for (int a = 0; a < 3; ++a)
#pragma unroll
      for (int c = 0; c < 3; ++c)
        wc3[a][c] = cw[(2 * g + h) * 9 + a * 3 + c] *
                    (0.125f * 1.4426950408889634f);
    const int ribase = (mt << 4) + lr;
#pragma unroll
    for (int dh = 0; dh < 2; ++dh) {
      const u16x8 qa = *(const u16x8*)&QPt[((size_t)(h * 34 + ribase + 0)) * 72 +
                                           (dh << 5) + lk];
      const u16x8 qb = *(const u16x8*)&QPt[((size_t)(h * 34 + ribase + 1)) * 72 +
                                           (dh << 5) + lk];
      const u16x8 qc = *(const u16x8*)&QPt[((size_t)(h * 34 + ribase + 2)) * 72 +
                                           (dh << 5) + lk];
#pragma unroll
      for (int c = 0; c < 3; ++c) {
#pragma unroll
        for (int e = 0; e < 8; ++e) {
          const float v = bf2f(qa[e]) * wc3[0][c] + bf2f(qb[e]) * wc3[1][c] +
                          bf2f(qc[e]) * wc3[2][c];
          qtf[c][dh][e] = (short)f2bf(v);
        }
      }
    }
  }
  // (B1 of step 0 fences all waves' Q reads before first Pt overwrite.)

  unsigned short* PtW = &QPt[(size_t)wid * 16 * 72];  // wave-private [16][72]

  // precomputed swizzled read offsets (row&7 = (lr+c)&7 for K, lr&7 for V)
  const unsigned char* kbB = KBASE(h) + lr * 128;  // + c*128 + nt*2048 + kofs
  int kofs[3][2];
#pragma unroll
  for (int c = 0; c < 3; ++c)
#pragma unroll
    for (int dh = 0; dh < 2; ++dh)
      kofs[c][dh] = (((((dh << 2) + lg) ^ ((lr + c) & 7)) << 4)) + c * 128;
  const unsigned char* vbB0 = VBASE(0) + lr * 128;
  const unsigned char* vbB1 = VBASE(1) + lr * 128;
  int vofs[2];
#pragma unroll
  for (int kj = 0; kj < 2; ++kj)
    vofs[kj] = ((((kj << 2) + lg) ^ (lr & 7)) << 4);

  float mreg = -3.0e38f, lreg = 0.f;  // for q-column qr = mt*16+lr (log2 units)
  f32x4 acc[2][4] = {};               // [v-head k][nt(d)]

  for (int s = 0; s < NKS; ++s) {
    // ---- phase 1: write staged K/V regs to LDS (swizzled chunks) ----
    {
      unsigned char* kr0 = KBASE(0) + krow * 128;
      unsigned char* kr1 = KBASE(1) + krow * 128;
      const int ksw = krow & 7;
      *(u16x8*)(kr0 + ((kc0 ^ ksw) << 4)) = kreg[0];
      *(u16x8*)(kr0 + (((kc0 + 1) ^ ksw) << 4)) = kreg[1];
      *(u16x8*)(kr1 + ((kc0 ^ ksw) << 4)) = kreg[2];
      *(u16x8*)(kr1 + (((kc0 + 1) ^ ksw) << 4)) = kreg[3];
      if (tid < 16) {
        const int k2sw = k2r & 7, k2c = tid & 7;
        *(u16x8*)(KBASE(0) + k2r * 128 + ((k2c ^ k2sw) << 4)) = kreg2[0];
        *(u16x8*)(KBASE(1) + k2r * 128 + ((k2c ^ k2sw) << 4)) = kreg2[1];
      }
      unsigned char* vr0 = VBASE(0) + vd * 128;
      unsigned char* vr1 = VBASE(1) + vd * 128;
      const int vsw = vd & 7, vcc = (tid & 3) << 1;
      *(u16x8*)(vr0 + ((vcc ^ vsw) << 4)) = vreg[0];
      *(u16x8*)(vr0 + (((vcc + 1) ^ vsw) << 4)) = vreg[1];
      *(u16x8*)(vr1 + ((vcc ^ vsw) << 4)) = vreg[2];
      *(u16x8*)(vr1 + (((vcc + 1) ^ vsw) << 4)) = vreg[3];
    }
    __syncthreads();  // B1

    // ---- phase 2: issue loads for step s+1 ----
    if (s + 1 < NKS) {
      const int j1 = (s + 1) << 6;
      const int gj = j1 - 1 + krow;
#pragma unroll
      for (int hh = 0; hh < 2; ++hh) {
        kreg[2 * hh] = *(const u16x8*)(Kz + hh * HSTR + (size_t)gj * 64 + kd0);
        kreg[2 * hh + 1] =
            *(const u16x8*)(Kz + hh * HSTR + (size_t)gj * 64 + kd0 + 8);
      }
      if (tid < 16) {
        const int gj2 = j1 - 1 + k2r;
#pragma unroll
        for (int hh = 0; hh < 2; ++hh) {
          u16x8 a = {};
          if (gj2 < N_)
            a = *(const u16x8*)(Kz + hh * HSTR + (size_t)gj2 * 64 + k2d);
          kreg2[hh] = a;
        }
      }
#pragma unroll
      for (int hh = 0; hh < 2; ++hh)
#pragma unroll
        for (int hf = 0; hf < 2; ++hf)
          vreg[2 * hh + hf] = *(const u16x8*)(Vz + hh * HSTR + (size_t)vd * 1024 +
                                              j1 + vc0 + (hf << 3));
    }

    // ---- phase 3: swapped conv-QK^T: racc[nt] cols=qr, rows=k-sub ----
    f32x4 racc[4] = {};
    __builtin_amdgcn_s_setprio(1);
#pragma unroll
    for (int c = 0; c < 3; ++c) {
#pragma unroll
      for (int dh = 0; dh < 2; ++dh) {
        const bf16x8 bq = qtf[c][dh];
#pragma unroll
        for (int nt = 0; nt < 4; ++nt) {
          const bf16x8 ak = *(const bf16x8*)(kbB + nt * 2048 + kofs[c][dh]);
          racc[nt] =
              __builtin_amdgcn_mfma_f32_16x16x32_bf16(ak, bq, racc[nt], 0, 0, 0);
        }
      }
    }
    __builtin_amdgcn_s_setprio(0);

    // ---- phase 4: per-lane online softmax (log2 domain, defer-max) ----
    {
      float pmax = fmaxf(fmaxf(racc[0][0], racc[0][1]),
                         fmaxf(racc[0][2], racc[0][3]));
#pragma unroll
      for (int nt = 1; nt < 4; ++nt)
        pmax = fmaxf(pmax, fmaxf(fmaxf(racc[nt][0], racc[nt][1]),
                                 fmaxf(racc[nt][2], racc[nt][3])));
      pmax = fmaxf(pmax, __shfl_xor(pmax, 16));
      pmax = fmaxf(pmax, __shfl_xor(pmax, 32));
      if (__any(pmax > mreg + 8.f)) {  // rare rescale path
        const float mn = fmaxf(mreg, pmax);
        const float alpha = exp2f(mreg - mn);
        mreg = mn;
        lreg *= alpha;
        float a4[4];
#pragma unroll
        for (int q = 0; q < 4; ++q)
          a4[q] = __shfl(alpha, (lg << 4) | ((lg << 2) + q));
#pragma unroll
        for (int k2 = 0; k2 < 2; ++k2)
#pragma unroll
          for (int nt = 0; nt < 4; ++nt)
#pragma unroll
            for (int q = 0; q < 4; ++q) acc[k2][nt][q] *= a4[q];
      }
      float rs = 0.f;
#pragma unroll
      for (int nt = 0; nt < 4; ++nt)
#pragma unroll
        for (int q = 0; q < 4; ++q) {
          const float p = exp2f(racc[nt][q] - mreg);
          racc[nt][q] = p;
          rs += p;
        }
      rs += __shfl_xor(rs, 16);
      rs += __shfl_xor(rs, 32);
      lreg += rs;
      // wave-private P~ store: row qr-sub = lr, k = 16nt+4lg+q (b64 packed)
#pragma unroll
      for (int nt = 0; nt < 4; ++nt) {
        ushort4 pw;
        pw.x = f2bf(racc[nt][0]); pw.y = f2bf(racc[nt][1]);
        pw.z = f2bf(racc[nt][2]); pw.w = f2bf(racc[nt][3]);
        *(ushort4*)&PtW[(size_t)lr * 72 + (nt << 4) + (lg << 2)] = pw;
      }
    }

    // ---- phase 5: PV (both v-heads) ----
    {
      bf16x8 paf[2];
      paf[0] = *(const bf16x8*)&PtW[(size_t)lr * 72 + lk];
      paf[1] = *(const bf16x8*)&PtW[(size_t)lr * 72 + 32 + lk];
      __builtin_amdgcn_s_setprio(1);
#pragma unroll
      for (int kj = 0; kj < 2; ++kj)
#pragma unroll
        for (int nt = 0; nt < 4; ++nt) {
          const bf16x8 bva = *(const bf16x8*)(vbB0 + nt * 2048 + vofs[kj]);
          const bf16x8 bvb = *(const bf16x8*)(vbB1 + nt * 2048 + vofs[kj]);
          acc[0][nt] = __builtin_amdgcn_mfma_f32_16x16x32_bf16(paf[kj], bva,
                                                               acc[0][nt], 0, 0, 0);
          acc[1][nt] = __builtin_amdgcn_mfma_f32_16x16x32_bf16(paf[kj], bvb,
                                                               acc[1][nt], 0, 0, 0);
        }
      __builtin_amdgcn_s_setprio(0);
    }
    __syncthreads();  // B3 (protects K/V LDS for next staging)
  }

  // ---- epilogue: O_k = sum_h hm[h,k]/l_h * A_hk ----
  if (lg == 0) lsum[h * 32 + (mt << 4) + lr] = lreg;
  __syncthreads();

  const float mw0 = hm[(g * 2 + h) * 2 + 0];
  const float mw1 = hm[(g * 2 + h) * 2 + 1];
  float* Os = (float*)smem;  // [2k][32 rows][68] floats (17408 B < 33280)
  if (h == 1) {
#pragma unroll
    for (int q = 0; q < 4; ++q) {
      const int row = (mt << 4) + (lg << 2) + q;
      const float f0 = mw0 / lsum[32 + row];
      const float f1 = mw1 / lsum[32 + row];
#pragma unroll
      for (int nt = 0; nt < 4; ++nt) {
        Os[(size_t)(0 * 32 + row) * 68 + (nt << 4) + lr] = acc[0][nt][q] * f0;
        Os[(size_t)(1 * 32 + row) * 68 + (nt << 4) + lr] = acc[1][nt][q] * f1;
      }
    }
  }
  __syncthreads();
  if (h == 0) {
#pragma unroll
    for (int q = 0; q < 4; ++q) {
      const int row = (mt << 4) + (lg << 2) + q;
      const int gi = i0 + row;
      const float f0 = mw0 / lsum[row];
      const float f1 = mw1 / lsum[row];
#pragma unroll
      for (int nt = 0; nt < 4; ++nt) {
        const float v0 =
            acc[0][nt][q] * f0 + Os[(size_t)(0 * 32 + row) * 68 + (nt << 4) + lr];
        const float v1 =
            acc[1][nt][q] * f1 + Os[(size_t)(1 * 32 + row) * 68 + (nt << 4) + lr];
        pvout[(size_t)(bb * N_ + gi) * C_ + (2 * g + 0) * 64 + (nt << 4) + lr] =
            f2bf(v0);
        pvout[(size_t)(bb * N_ + gi) * C_ + (2 * g + 1) * 64 + (nt << 4) + lr] =
            f2bf(v1);
      }
    }
  }
#undef KBASE
#undef VBASE
}

extern "C" void kernel_launch(void* const* d_in, const int* in_sizes, int n_in,
                              void* d_out, int out_size, void* d_ws, size_t ws_size,
                              hipStream_t stream) {
  const float* query = (const float*)d_in[0];
  const float* key   = (const float*)d_in[1];
  const float* value = (const float*)d_in[2];
  const float* Wq = (const float*)d_in[3];
  const float* bq = (const float*)d_in[4];
  const float* Wk = (const float*)d_in[5];
  const float* bk = (const float*)d_in[6];
  const float* Wv = (const float*)d_in[7];
  const float* bv = (const float*)d_in[8];
  const float* cw = (const float*)d_in[9];
  const float* hm = (const float*)d_in[10];
  const float* Wo = (const float*)d_in[11];
  const float* bo = (const float*)d_in[12];
  float* out = (float*)d_out;

  char* ws = (char*)d_ws;
  const size_t SZ_BF = (size_t)B_ * H_ * N_ * 64 * 2;  // 12,582,912 B
  unsigned short* Qb = (unsigned short*)ws;
  unsigned short* Kb = (unsigned short*)(ws + SZ_BF);
  unsigned short* Vt = (unsigned short*)(ws + 2 * SZ_BF);   // (B,H,D,N)
  unsigned short* pvb = (unsigned short*)(ws + 3 * SZ_BF);  // bf16 (B,N,C)
  unsigned short* Xb = (unsigned short*)(ws + 4 * SZ_BF);   // q,k,v bf16
  unsigned short* Wb = (unsigned short*)(ws + 7 * SZ_BF);   // Wq,Wk,Wv,Wo bf16

  const dim3 blk(256);
  cvtX<<<dim3(3072, 3), blk, 0, stream>>>(query, key, value, Xb);
  cvtW<<<dim3(288, 4), blk, 0, stream>>>(Wq, Wk, Wv, Wo, Wb);
  proj3<<<dim3(1152), blk, 0, stream>>>(Xb, Wb, bq, bk, bv, Qb, Kb, Vt);
  fused_attn<<<dim3(1536), blk, 0, stream>>>(Qb, Kb, Vt, cw, hm, pvb);
  oproj<<<dim3(384), blk, 0, stream>>>(pvb, Wb, bo, out);
}